// Round 3
// baseline (9434.628 us; speedup 1.0000x reference)
//
#include <hip/hip_runtime.h>
#include <hip/hip_bf16.h>

// Encoder: L=6, D=512, H=8, HD=64, F=2048, V=32000, N=2, S=2048, NS=4096
// Inputs: float tensors are fp32 (per reference dtypes); ints int32. Output fp32.
// Internal: h fp32 in ws; Q,K,V,attn-out bf16 in ws (our own encoding). 25.2 MB total.

#define NS_TOK 4096
#define DMODEL 512
#define NHEAD 8
#define HDIM 64
#define FFDIM 2048
#define SEQ 2048
#define NB 2

typedef __hip_bfloat16 bf16;

__device__ __forceinline__ float bf2f(bf16 x) { return __bfloat162float(x); }
__device__ __forceinline__ bf16 f2bf(float x) { return __float2bfloat16(x); }
__device__ __forceinline__ float2 bf2x2(unsigned int u) {
    float2 r;
    r.x = __uint_as_float(u << 16);
    r.y = __uint_as_float(u & 0xffff0000u);
    return r;
}

__device__ __forceinline__ float block_sum(float v, float* red) {
    int t = threadIdx.x;
    red[t] = v;
    __syncthreads();
    #pragma unroll
    for (int s = 128; s > 0; s >>= 1) {
        if (t < s) red[t] += red[t + s];
        __syncthreads();
    }
    float r = red[0];
    __syncthreads();
    return r;
}

// ---------------- embed: h[row, :] = emb[src[row], :] * sqrt(D) ----------------
__global__ __launch_bounds__(256) void k_embed(const int* __restrict__ src,
                                               const float* __restrict__ emb,
                                               float* __restrict__ h) {
    int row = blockIdx.x;
    int t = threadIdx.x;
    int tok = src[row];
    const float* e = emb + (size_t)tok * DMODEL;
    float* o = h + (size_t)row * DMODEL;
    o[t]       = e[t]       * 22.62741699796952f;
    o[t + 256] = e[t + 256] * 22.62741699796952f;
}

// ---------------- QKV projection (per-head 64x64, shared across heads) ----------
__global__ __launch_bounds__(256) void k_qkv(const float* __restrict__ h,
    const float* __restrict__ Wq, const float* __restrict__ bq,
    const float* __restrict__ Wk, const float* __restrict__ bk,
    const float* __restrict__ Wv, const float* __restrict__ bv,
    bf16* __restrict__ Qo, bf16* __restrict__ Ko, bf16* __restrict__ Vo) {
    __shared__ float x[4][DMODEL];
    int r0 = blockIdx.x * 4;
    int t = threadIdx.x;
    for (int j = t; j < 4 * DMODEL; j += 256) x[j >> 9][j & 511] = h[(size_t)r0 * DMODEL + j];
    __syncthreads();
    const float* Ws[3] = {Wq, Wk, Wv};
    const float* Bs[3] = {bq, bk, bv};
    bf16* Os[3] = {Qo, Ko, Vo};
    for (int tn = 0; tn < 3; ++tn) {
        const float* W = Ws[tn];
        bf16* O = Os[tn];
        for (int jo = 0; jo < 2; ++jo) {
            int o = t + jo * 256;
            int e = o & 63, hd = o >> 6;
            const float4* w4 = (const float4*)(W + e * HDIM);
            float a0 = 0.f, a1 = 0.f, a2 = 0.f, a3 = 0.f;
            #pragma unroll
            for (int j = 0; j < 16; ++j) {
                float4 wv = w4[j];
                int d = hd * HDIM + j * 4;
                float4 x0 = *(const float4*)&x[0][d];
                float4 x1 = *(const float4*)&x[1][d];
                float4 x2 = *(const float4*)&x[2][d];
                float4 x3 = *(const float4*)&x[3][d];
                a0 += x0.x * wv.x + x0.y * wv.y + x0.z * wv.z + x0.w * wv.w;
                a1 += x1.x * wv.x + x1.y * wv.y + x1.z * wv.z + x1.w * wv.w;
                a2 += x2.x * wv.x + x2.y * wv.y + x2.z * wv.z + x2.w * wv.w;
                a3 += x3.x * wv.x + x3.y * wv.y + x3.z * wv.z + x3.w * wv.w;
            }
            float bias = Bs[tn][e];
            O[(size_t)(r0 + 0) * DMODEL + o] = f2bf(a0 + bias);
            O[(size_t)(r0 + 1) * DMODEL + o] = f2bf(a1 + bias);
            O[(size_t)(r0 + 2) * DMODEL + o] = f2bf(a2 + bias);
            O[(size_t)(r0 + 3) * DMODEL + o] = f2bf(a3 + bias);
        }
    }
}

// ---------------- flash attention: 32-query tile, 64-key tiles, online softmax --
__global__ __launch_bounds__(256) void k_attn(const bf16* __restrict__ Qb,
                                              const bf16* __restrict__ Kb,
                                              const bf16* __restrict__ Vb,
                                              const int* __restrict__ mask,
                                              bf16* __restrict__ Ab) {
    __shared__ float Qt[32][64];
    __shared__ float Kt[64][68];
    __shared__ float Vt[64][64];
    __shared__ float St[32][65];
    __shared__ float mS[32], lS[32], aS[32];
    int t = threadIdx.x;
    int q0 = blockIdx.x * 32;
    int hh = blockIdx.y;
    int n = blockIdx.z;
    size_t base = ((size_t)n * SEQ) * DMODEL + hh * HDIM;   // element offset
    const float SCALE = 0.044194173824159216f;  // 1/sqrt(512)

    {   // stage Q tile (bf16 -> f32): 32 rows x 8 uint4 (8 bf16 each)
        int i = t >> 3, g = t & 7;
        uint4 u = *(const uint4*)(Qb + base + (size_t)(q0 + i) * DMODEL + g * 8);
        float2 a0 = bf2x2(u.x), a1 = bf2x2(u.y), a2 = bf2x2(u.z), a3 = bf2x2(u.w);
        float4 lo = {a0.x, a0.y, a1.x, a1.y}, hi = {a2.x, a2.y, a3.x, a3.y};
        *(float4*)&Qt[i][g * 8]     = lo;
        *(float4*)&Qt[i][g * 8 + 4] = hi;
    }
    if (t < 32) { mS[t] = -1.0e30f; lS[t] = 0.f; }
    float4 O0 = {0, 0, 0, 0}, O1 = {0, 0, 0, 0};
    int kk = t & 63, grp = t >> 6;   // scores: key kk, rows grp*8..+8
    int j4 = t & 15, ig = t >> 4;    // PV: dims j4*4..+4, rows ig*2, ig*2+1
    __syncthreads();

    for (int k0 = 0; k0 < SEQ; k0 += 64) {
        #pragma unroll
        for (int rep = 0; rep < 2; ++rep) {   // stage K,V (64 rows x 8 uint4 each)
            int idx = t + 256 * rep;
            int r = idx >> 3, g = idx & 7;
            size_t ga = base + (size_t)(k0 + r) * DMODEL + g * 8;
            uint4 uk = *(const uint4*)(Kb + ga);
            uint4 uv = *(const uint4*)(Vb + ga);
            float2 a0 = bf2x2(uk.x), a1 = bf2x2(uk.y), a2 = bf2x2(uk.z), a3 = bf2x2(uk.w);
            float4 lo = {a0.x, a0.y, a1.x, a1.y}, hi = {a2.x, a2.y, a3.x, a3.y};
            *(float4*)&Kt[r][g * 8]     = lo;
            *(float4*)&Kt[r][g * 8 + 4] = hi;
            a0 = bf2x2(uv.x); a1 = bf2x2(uv.y); a2 = bf2x2(uv.z); a3 = bf2x2(uv.w);
            float4 lo2 = {a0.x, a0.y, a1.x, a1.y}, hi2 = {a2.x, a2.y, a3.x, a3.y};
            *(float4*)&Vt[r][g * 8]     = lo2;
            *(float4*)&Vt[r][g * 8 + 4] = hi2;
        }
        __syncthreads();
        {   // scores: thread computes 8 rows for its key kk
            float acc[8];
            #pragma unroll
            for (int r2 = 0; r2 < 8; ++r2) acc[r2] = 0.f;
            #pragma unroll
            for (int j = 0; j < 16; ++j) {
                float4 kv = *(const float4*)&Kt[kk][j * 4];
                #pragma unroll
                for (int r2 = 0; r2 < 8; ++r2) {
                    float4 qv = *(const float4*)&Qt[grp * 8 + r2][j * 4];
                    acc[r2] += qv.x * kv.x + qv.y * kv.y + qv.z * kv.z + qv.w * kv.w;
                }
            }
            int mk = mask[n * SEQ + k0 + kk];
            #pragma unroll
            for (int r2 = 0; r2 < 8; ++r2)
                St[grp * 8 + r2][kk] = mk ? acc[r2] * SCALE : -4.4194e8f;
        }
        __syncthreads();
        if (t < 32) {   // online softmax update, one thread per query row
            float mo = mS[t], mn = mo;
            for (int k2 = 0; k2 < 64; ++k2) mn = fmaxf(mn, St[t][k2]);
            float sum = 0.f;
            for (int k2 = 0; k2 < 64; ++k2) {
                float p = __expf(St[t][k2] - mn);
                St[t][k2] = p;
                sum += p;
            }
            float al = __expf(mo - mn);
            mS[t] = mn;
            lS[t] = lS[t] * al + sum;
            aS[t] = al;
        }
        __syncthreads();
        {   // PV accumulate with rescale
            int i0 = ig * 2, i1 = i0 + 1;
            float a0 = aS[i0], a1 = aS[i1];
            O0.x *= a0; O0.y *= a0; O0.z *= a0; O0.w *= a0;
            O1.x *= a1; O1.y *= a1; O1.z *= a1; O1.w *= a1;
            for (int k2 = 0; k2 < 64; ++k2) {
                float4 vv = *(const float4*)&Vt[k2][j4 * 4];
                float p0 = St[i0][k2], p1 = St[i1][k2];
                O0.x += vv.x * p0; O0.y += vv.y * p0; O0.z += vv.z * p0; O0.w += vv.w * p0;
                O1.x += vv.x * p1; O1.y += vv.y * p1; O1.z += vv.z * p1; O1.w += vv.w * p1;
            }
        }
        __syncthreads();
    }
    {
        int i0 = ig * 2, i1 = i0 + 1;
        float v0 = 1.f / lS[i0], v1 = 1.f / lS[i1];
        bf16* d0 = Ab + base + (size_t)(q0 + i0) * DMODEL + j4 * 4;
        bf16* d1 = Ab + base + (size_t)(q0 + i1) * DMODEL + j4 * 4;
        d0[0] = f2bf(O0.x * v0); d0[1] = f2bf(O0.y * v0);
        d0[2] = f2bf(O0.z * v0); d0[3] = f2bf(O0.w * v0);
        d1[0] = f2bf(O1.x * v1); d1[1] = f2bf(O1.y * v1);
        d1[2] = f2bf(O1.z * v1); d1[3] = f2bf(O1.w * v1);
    }
}

// ---------------- output proj + residual + LN1 ----------------
__global__ __launch_bounds__(256) void k_oproj(const bf16* __restrict__ Ain,
    const float* __restrict__ Wo, const float* __restrict__ bo,
    const float* __restrict__ g, const float* __restrict__ b,
    float* __restrict__ h) {
    __shared__ float a[4][DMODEL];
    __shared__ float rbuf[4][DMODEL];
    __shared__ float red[256];
    int r0 = blockIdx.x * 4;
    int t = threadIdx.x;
    {   // stage bf16 -> f32: 1024 uints = 2048 bf16
        const uint* ap = (const uint*)(Ain + (size_t)r0 * DMODEL);
        for (int p = t; p < 1024; p += 256) {
            float2 f = bf2x2(ap[p]);
            int row = p >> 8, col = (p & 255) * 2;
            a[row][col] = f.x;
            a[row][col + 1] = f.y;
        }
    }
    __syncthreads();
    for (int jo = 0; jo < 2; ++jo) {
        int o = t + jo * 256;
        const float4* w = (const float4*)(Wo + (size_t)o * DMODEL);
        float acc[4] = {0.f, 0.f, 0.f, 0.f};
        for (int j = 0; j < 128; ++j) {
            float4 wv = w[j];
            #pragma unroll
            for (int r = 0; r < 4; ++r) {
                float4 xv = *(const float4*)&a[r][j * 4];
                acc[r] += xv.x * wv.x + xv.y * wv.y + xv.z * wv.z + xv.w * wv.w;
            }
        }
        float bias = bo[o];
        #pragma unroll
        for (int r = 0; r < 4; ++r)
            rbuf[r][o] = h[(size_t)(r0 + r) * DMODEL + o] + acc[r] + bias;
    }
    __syncthreads();
    for (int r = 0; r < 4; ++r) {
        float s = block_sum(rbuf[r][t] + rbuf[r][t + 256], red);
        float mean = s * (1.f / DMODEL);
        float d0 = rbuf[r][t] - mean, d1 = rbuf[r][t + 256] - mean;
        float vs = block_sum(d0 * d0 + d1 * d1, red);
        float rstd = rsqrtf(vs * (1.f / DMODEL) + 1e-5f);
        h[(size_t)(r0 + r) * DMODEL + t]       = d0 * rstd * g[t]       + b[t];
        h[(size_t)(r0 + r) * DMODEL + t + 256] = d1 * rstd * g[t + 256] + b[t + 256];
    }
}

// ---------------- fused FFN: relu(h W1^T + b1) W2^T + b2 + residual + LN2 -------
// Writes LN output to `out` (== h for layers 0-4, == d_out for layer 5).
__global__ __launch_bounds__(256) void k_ffn(const float* __restrict__ h,
    const float* __restrict__ W1, const float* __restrict__ b1,
    const float* __restrict__ W2, const float* __restrict__ b2,
    const float* __restrict__ g, const float* __restrict__ b,
    float* __restrict__ out) {
    __shared__ float x[4][DMODEL];     // 8 KB; reused as rbuf after FFN1
    __shared__ float f1[4][FFDIM];     // 32 KB
    __shared__ float red[256];         // 1 KB
    int r0 = blockIdx.x * 4;
    int t = threadIdx.x;
    for (int j = t; j < 4 * DMODEL; j += 256) x[j >> 9][j & 511] = h[(size_t)r0 * DMODEL + j];
    __syncthreads();
    // FFN1 -> f1 (LDS)
    for (int jf = 0; jf < 8; ++jf) {
        int f = t + jf * 256;
        const float4* w = (const float4*)(W1 + (size_t)f * DMODEL);
        float acc[4] = {0.f, 0.f, 0.f, 0.f};
        for (int j = 0; j < 128; ++j) {
            float4 wv = w[j];
            #pragma unroll
            for (int r = 0; r < 4; ++r) {
                float4 xv = *(const float4*)&x[r][j * 4];
                acc[r] += xv.x * wv.x + xv.y * wv.y + xv.z * wv.z + xv.w * wv.w;
            }
        }
        float bias = b1[f];
        #pragma unroll
        for (int r = 0; r < 4; ++r)
            f1[r][f] = fmaxf(acc[r] + bias, 0.f);
    }
    __syncthreads();
    // FFN2 + residual into rbuf (= x, reused; x no longer needed)
    float (*rbuf)[DMODEL] = x;
    for (int jo = 0; jo < 2; ++jo) {
        int o = t + jo * 256;
        const float4* w = (const float4*)(W2 + (size_t)o * FFDIM);
        float acc[4] = {0.f, 0.f, 0.f, 0.f};
        for (int j = 0; j < 512; ++j) {
            float4 wv = w[j];
            #pragma unroll
            for (int r = 0; r < 4; ++r) {
                float4 xv = *(const float4*)&f1[r][j * 4];
                acc[r] += xv.x * wv.x + xv.y * wv.y + xv.z * wv.z + xv.w * wv.w;
            }
        }
        float bias = b2[o];
        #pragma unroll
        for (int r = 0; r < 4; ++r)
            rbuf[r][o] = h[(size_t)(r0 + r) * DMODEL + o] + acc[r] + bias;
    }
    __syncthreads();
    for (int r = 0; r < 4; ++r) {
        float s = block_sum(rbuf[r][t] + rbuf[r][t + 256], red);
        float mean = s * (1.f / DMODEL);
        float d0 = rbuf[r][t] - mean, d1 = rbuf[r][t + 256] - mean;
        float vs = block_sum(d0 * d0 + d1 * d1, red);
        float rstd = rsqrtf(vs * (1.f / DMODEL) + 1e-5f);
        out[(size_t)(r0 + r) * DMODEL + t]       = d0 * rstd * g[t]       + b[t];
        out[(size_t)(r0 + r) * DMODEL + t + 256] = d1 * rstd * g[t + 256] + b[t + 256];
    }
}

extern "C" void kernel_launch(void* const* d_in, const int* in_sizes, int n_in,
                              void* d_out, int out_size, void* d_ws, size_t ws_size,
                              hipStream_t stream) {
    const int*   src  = (const int*)d_in[0];
    const int*   mask = (const int*)d_in[1];
    const float* emb  = (const float*)d_in[2];
    const float* Wq   = (const float*)d_in[3];
    const float* bq   = (const float*)d_in[4];
    const float* Wk   = (const float*)d_in[5];
    const float* bk   = (const float*)d_in[6];
    const float* Wv   = (const float*)d_in[7];
    const float* bv   = (const float*)d_in[8];
    const float* Wo   = (const float*)d_in[9];
    const float* bo   = (const float*)d_in[10];
    const float* W1   = (const float*)d_in[11];
    const float* b1   = (const float*)d_in[12];
    const float* W2   = (const float*)d_in[13];
    const float* b2   = (const float*)d_in[14];
    const float* ln1g = (const float*)d_in[15];
    const float* ln1b = (const float*)d_in[16];
    const float* ln2g = (const float*)d_in[17];
    const float* ln2b = (const float*)d_in[18];

    float* h  = (float*)d_ws;                              // 4096*512 f32 = 8.39 MB
    bf16*  Qb = (bf16*)(h + (size_t)NS_TOK * DMODEL);      // 4.19 MB each
    bf16*  Kb = Qb + (size_t)NS_TOK * DMODEL;
    bf16*  Vb = Kb + (size_t)NS_TOK * DMODEL;
    bf16*  Ab = Vb + (size_t)NS_TOK * DMODEL;              // total 25.2 MB

    k_embed<<<NS_TOK, 256, 0, stream>>>(src, emb, h);
    for (int l = 0; l < 6; ++l) {
        k_qkv<<<NS_TOK / 4, 256, 0, stream>>>(h,
            Wq + (size_t)l * HDIM * HDIM, bq + l * HDIM,
            Wk + (size_t)l * HDIM * HDIM, bk + l * HDIM,
            Wv + (size_t)l * HDIM * HDIM, bv + l * HDIM,
            Qb, Kb, Vb);
        k_attn<<<dim3(SEQ / 32, NHEAD, NB), 256, 0, stream>>>(Qb, Kb, Vb, mask, Ab);
        k_oproj<<<NS_TOK / 4, 256, 0, stream>>>(Ab,
            Wo + (size_t)l * DMODEL * DMODEL, bo + l * DMODEL,
            ln1g + l * DMODEL, ln1b + l * DMODEL, h);
        float* ffn_out = (l == 5) ? (float*)d_out : h;
        k_ffn<<<NS_TOK / 4, 256, 0, stream>>>(h,
            W1 + (size_t)l * FFDIM * DMODEL, b1 + l * FFDIM,
            W2 + (size_t)l * DMODEL * FFDIM, b2 + l * DMODEL,
            ln2g + l * DMODEL, ln2b + l * DMODEL, ffn_out);
    }
}

// Round 4
// 3693.069 us; speedup vs baseline: 2.5547x; 2.5547x over previous
//
#include <hip/hip_runtime.h>
#include <hip/hip_bf16.h>

// Encoder: L=6, D=512, H=8, HD=64, F=2048, V=32000, N=2, S=2048, NS=4096
// fp32 inputs/outputs. Internal: h fp32; Q/K/V/A bf16; FFN+oproj via bf16 MFMA GEMM.
// ws layout: h(8.39) | hb(4.19) | P(8.39) | Qb Kb Vb Ab (16.78, aliased by F1b) = 37.8 MB

#define NS_TOK 4096
#define DMODEL 512
#define NHEAD 8
#define HDIM 64
#define FFDIM 2048
#define SEQ 2048
#define NB 2

typedef __hip_bfloat16 bf16;
typedef __attribute__((ext_vector_type(8))) short short8;
typedef __attribute__((ext_vector_type(4))) float floatx4;

__device__ __forceinline__ float bf2f(bf16 x) { return __bfloat162float(x); }
__device__ __forceinline__ bf16 f2bf(float x) { return __float2bfloat16(x); }
__device__ __forceinline__ short bfbits(float x) {
    bf16 h = __float2bfloat16(x);
    return *reinterpret_cast<short*>(&h);
}
__device__ __forceinline__ float2 bf2x2(unsigned int u) {
    float2 r;
    r.x = __uint_as_float(u << 16);
    r.y = __uint_as_float(u & 0xffff0000u);
    return r;
}

// ---------------- embed ----------------
__global__ __launch_bounds__(256) void k_embed(const int* __restrict__ src,
                                               const float* __restrict__ emb,
                                               float* __restrict__ h) {
    int row = blockIdx.x;
    int t = threadIdx.x;
    int tok = src[row];
    const float* e = emb + (size_t)tok * DMODEL;
    float* o = h + (size_t)row * DMODEL;
    o[t]       = e[t]       * 22.62741699796952f;
    o[t + 256] = e[t + 256] * 22.62741699796952f;
}

// ---------------- QKV projection (per-head 64x64, shared across heads) ----------
__global__ __launch_bounds__(256) void k_qkv(const float* __restrict__ h,
    const float* __restrict__ Wq, const float* __restrict__ bq,
    const float* __restrict__ Wk, const float* __restrict__ bk,
    const float* __restrict__ Wv, const float* __restrict__ bv,
    bf16* __restrict__ Qo, bf16* __restrict__ Ko, bf16* __restrict__ Vo) {
    __shared__ float x[4][DMODEL];
    int r0 = blockIdx.x * 4;
    int t = threadIdx.x;
    for (int j = t; j < 4 * DMODEL; j += 256) x[j >> 9][j & 511] = h[(size_t)r0 * DMODEL + j];
    __syncthreads();
    const float* Ws[3] = {Wq, Wk, Wv};
    const float* Bs[3] = {bq, bk, bv};
    bf16* Os[3] = {Qo, Ko, Vo};
    for (int tn = 0; tn < 3; ++tn) {
        const float* W = Ws[tn];
        bf16* O = Os[tn];
        for (int jo = 0; jo < 2; ++jo) {
            int o = t + jo * 256;
            int e = o & 63, hd = o >> 6;
            const float4* w4 = (const float4*)(W + e * HDIM);
            float a0 = 0.f, a1 = 0.f, a2 = 0.f, a3 = 0.f;
            #pragma unroll
            for (int j = 0; j < 16; ++j) {
                float4 wv = w4[j];
                int d = hd * HDIM + j * 4;
                float4 x0 = *(const float4*)&x[0][d];
                float4 x1 = *(const float4*)&x[1][d];
                float4 x2 = *(const float4*)&x[2][d];
                float4 x3 = *(const float4*)&x[3][d];
                a0 += x0.x * wv.x + x0.y * wv.y + x0.z * wv.z + x0.w * wv.w;
                a1 += x1.x * wv.x + x1.y * wv.y + x1.z * wv.z + x1.w * wv.w;
                a2 += x2.x * wv.x + x2.y * wv.y + x2.z * wv.z + x2.w * wv.w;
                a3 += x3.x * wv.x + x3.y * wv.y + x3.z * wv.z + x3.w * wv.w;
            }
            float bias = Bs[tn][e];
            O[(size_t)(r0 + 0) * DMODEL + o] = f2bf(a0 + bias);
            O[(size_t)(r0 + 1) * DMODEL + o] = f2bf(a1 + bias);
            O[(size_t)(r0 + 2) * DMODEL + o] = f2bf(a2 + bias);
            O[(size_t)(r0 + 3) * DMODEL + o] = f2bf(a3 + bias);
        }
    }
}

// ---------------- flash attention (unchanged from round 3) ----------------
__global__ __launch_bounds__(256) void k_attn(const bf16* __restrict__ Qb,
                                              const bf16* __restrict__ Kb,
                                              const bf16* __restrict__ Vb,
                                              const int* __restrict__ mask,
                                              bf16* __restrict__ Ab) {
    __shared__ float Qt[32][64];
    __shared__ float Kt[64][68];
    __shared__ float Vt[64][64];
    __shared__ float St[32][65];
    __shared__ float mS[32], lS[32], aS[32];
    int t = threadIdx.x;
    int q0 = blockIdx.x * 32;
    int hh = blockIdx.y;
    int n = blockIdx.z;
    size_t base = ((size_t)n * SEQ) * DMODEL + hh * HDIM;
    const float SCALE = 0.044194173824159216f;  // 1/sqrt(512)

    {
        int i = t >> 3, g = t & 7;
        uint4 u = *(const uint4*)(Qb + base + (size_t)(q0 + i) * DMODEL + g * 8);
        float2 a0 = bf2x2(u.x), a1 = bf2x2(u.y), a2 = bf2x2(u.z), a3 = bf2x2(u.w);
        float4 lo = {a0.x, a0.y, a1.x, a1.y}, hi = {a2.x, a2.y, a3.x, a3.y};
        *(float4*)&Qt[i][g * 8]     = lo;
        *(float4*)&Qt[i][g * 8 + 4] = hi;
    }
    if (t < 32) { mS[t] = -1.0e30f; lS[t] = 0.f; }
    float4 O0 = {0, 0, 0, 0}, O1 = {0, 0, 0, 0};
    int kk = t & 63, grp = t >> 6;
    int j4 = t & 15, ig = t >> 4;
    __syncthreads();

    for (int k0 = 0; k0 < SEQ; k0 += 64) {
        #pragma unroll
        for (int rep = 0; rep < 2; ++rep) {
            int idx = t + 256 * rep;
            int r = idx >> 3, g = idx & 7;
            size_t ga = base + (size_t)(k0 + r) * DMODEL + g * 8;
            uint4 uk = *(const uint4*)(Kb + ga);
            uint4 uv = *(const uint4*)(Vb + ga);
            float2 a0 = bf2x2(uk.x), a1 = bf2x2(uk.y), a2 = bf2x2(uk.z), a3 = bf2x2(uk.w);
            float4 lo = {a0.x, a0.y, a1.x, a1.y}, hi = {a2.x, a2.y, a3.x, a3.y};
            *(float4*)&Kt[r][g * 8]     = lo;
            *(float4*)&Kt[r][g * 8 + 4] = hi;
            a0 = bf2x2(uv.x); a1 = bf2x2(uv.y); a2 = bf2x2(uv.z); a3 = bf2x2(uv.w);
            float4 lo2 = {a0.x, a0.y, a1.x, a1.y}, hi2 = {a2.x, a2.y, a3.x, a3.y};
            *(float4*)&Vt[r][g * 8]     = lo2;
            *(float4*)&Vt[r][g * 8 + 4] = hi2;
        }
        __syncthreads();
        {
            float acc[8];
            #pragma unroll
            for (int r2 = 0; r2 < 8; ++r2) acc[r2] = 0.f;
            #pragma unroll
            for (int j = 0; j < 16; ++j) {
                float4 kv = *(const float4*)&Kt[kk][j * 4];
                #pragma unroll
                for (int r2 = 0; r2 < 8; ++r2) {
                    float4 qv = *(const float4*)&Qt[grp * 8 + r2][j * 4];
                    acc[r2] += qv.x * kv.x + qv.y * kv.y + qv.z * kv.z + qv.w * kv.w;
                }
            }
            int mk = mask[n * SEQ + k0 + kk];
            #pragma unroll
            for (int r2 = 0; r2 < 8; ++r2)
                St[grp * 8 + r2][kk] = mk ? acc[r2] * SCALE : -4.4194e8f;
        }
        __syncthreads();
        if (t < 32) {
            float mo = mS[t], mn = mo;
            for (int k2 = 0; k2 < 64; ++k2) mn = fmaxf(mn, St[t][k2]);
            float sum = 0.f;
            for (int k2 = 0; k2 < 64; ++k2) {
                float p = __expf(St[t][k2] - mn);
                St[t][k2] = p;
                sum += p;
            }
            float al = __expf(mo - mn);
            mS[t] = mn;
            lS[t] = lS[t] * al + sum;
            aS[t] = al;
        }
        __syncthreads();
        {
            int i0 = ig * 2, i1 = i0 + 1;
            float a0 = aS[i0], a1 = aS[i1];
            O0.x *= a0; O0.y *= a0; O0.z *= a0; O0.w *= a0;
            O1.x *= a1; O1.y *= a1; O1.z *= a1; O1.w *= a1;
            for (int k2 = 0; k2 < 64; ++k2) {
                float4 vv = *(const float4*)&Vt[k2][j4 * 4];
                float p0 = St[i0][k2], p1 = St[i1][k2];
                O0.x += vv.x * p0; O0.y += vv.y * p0; O0.z += vv.z * p0; O0.w += vv.w * p0;
                O1.x += vv.x * p1; O1.y += vv.y * p1; O1.z += vv.z * p1; O1.w += vv.w * p1;
            }
        }
        __syncthreads();
    }
    {
        int i0 = ig * 2, i1 = i0 + 1;
        float v0 = 1.f / lS[i0], v1 = 1.f / lS[i1];
        bf16* d0 = Ab + base + (size_t)(q0 + i0) * DMODEL + j4 * 4;
        bf16* d1 = Ab + base + (size_t)(q0 + i1) * DMODEL + j4 * 4;
        d0[0] = f2bf(O0.x * v0); d0[1] = f2bf(O0.y * v0);
        d0[2] = f2bf(O0.z * v0); d0[3] = f2bf(O0.w * v0);
        d1[0] = f2bf(O1.x * v1); d1[1] = f2bf(O1.y * v1);
        d1[2] = f2bf(O1.z * v1); d1[3] = f2bf(O1.w * v1);
    }
}

// ---------------- MFMA GEMM: C[M,N] = A[M,K](bf16) @ W[N,K](f32->bf16)^T --------
// MT=128: 4 waves in 2x2, each 64x64 (4x4 frags). MT=64: 4 waves in 1x4, each 64x32.
// LDS rows padded to 40 shorts (80 B): worst 2-way bank conflict (free, m136).
// RELU path: +bias, relu, store bf16 to outB. Else: +bias +resid, store f32 to outF.
template<int MT, bool RELU>
__global__ __launch_bounds__(256) void k_gemm(const bf16* __restrict__ A,
    const float* __restrict__ W, const float* __restrict__ bias, int K, int N,
    const float* __restrict__ resid, float* __restrict__ outF, bf16* __restrict__ outB) {
    constexpr int FI = 4;
    constexpr int FJ = (MT == 128) ? 4 : 2;
    __shared__ short As[MT * 40];
    __shared__ short Bs[128 * 40];
    int t = threadIdx.x, lane = t & 63, w = t >> 6;
    int m0 = blockIdx.x * MT, n0 = blockIdx.y * 128;
    int wrow = (MT == 128) ? (w >> 1) * 64 : 0;
    int wcol = (MT == 128) ? (w & 1) * 64 : w * 32;
    int quad = lane >> 4, mrow = lane & 15;
    floatx4 acc[FI][FJ];
    #pragma unroll
    for (int fi = 0; fi < FI; ++fi)
        #pragma unroll
        for (int fj = 0; fj < FJ; ++fj)
            #pragma unroll
            for (int r = 0; r < 4; ++r) acc[fi][fj][r] = 0.f;

    for (int k0 = 0; k0 < K; k0 += 32) {
        __syncthreads();
        #pragma unroll
        for (int i = 0; i < MT / 64; ++i) {      // A tile: MT x 32 bf16
            int idx = t + i * 256;
            int row = idx >> 2, q = idx & 3;
            uint4 u = *(const uint4*)(A + (size_t)(m0 + row) * K + k0 + q * 8);
            *(uint4*)&As[row * 40 + q * 8] = u;
        }
        #pragma unroll
        for (int i = 0; i < 2; ++i) {            // W tile: 128 x 32 f32 -> bf16
            int idx = t + i * 256;
            int row = idx >> 2, q = idx & 3;
            const float* src = W + (size_t)(n0 + row) * K + k0 + q * 8;
            float4 f0 = *(const float4*)src;
            float4 f1 = *(const float4*)(src + 4);
            short8 sv;
            sv[0] = bfbits(f0.x); sv[1] = bfbits(f0.y);
            sv[2] = bfbits(f0.z); sv[3] = bfbits(f0.w);
            sv[4] = bfbits(f1.x); sv[5] = bfbits(f1.y);
            sv[6] = bfbits(f1.z); sv[7] = bfbits(f1.w);
            *(short8*)&Bs[row * 40 + q * 8] = sv;
        }
        __syncthreads();
        short8 af[FI], bfr[FJ];
        #pragma unroll
        for (int fi = 0; fi < FI; ++fi)
            af[fi] = *(short8*)&As[(wrow + fi * 16 + mrow) * 40 + quad * 8];
        #pragma unroll
        for (int fj = 0; fj < FJ; ++fj)
            bfr[fj] = *(short8*)&Bs[(wcol + fj * 16 + mrow) * 40 + quad * 8];
        #pragma unroll
        for (int fi = 0; fi < FI; ++fi)
            #pragma unroll
            for (int fj = 0; fj < FJ; ++fj)
                acc[fi][fj] = __builtin_amdgcn_mfma_f32_16x16x32_bf16(
                    af[fi], bfr[fj], acc[fi][fj], 0, 0, 0);
    }
    // epilogue: C row = quad*4+r, col = mrow (m89-verified layout)
    #pragma unroll
    for (int fi = 0; fi < FI; ++fi)
        #pragma unroll
        for (int fj = 0; fj < FJ; ++fj) {
            int col = n0 + wcol + fj * 16 + mrow;
            float bv = bias[col];
            #pragma unroll
            for (int r = 0; r < 4; ++r) {
                int row = m0 + wrow + fi * 16 + quad * 4 + r;
                float v = acc[fi][fj][r] + bv;
                if (RELU) {
                    outB[(size_t)row * N + col] = f2bf(fmaxf(v, 0.f));
                } else {
                    outF[(size_t)row * N + col] = v + resid[(size_t)row * N + col];
                }
            }
        }
}

// ---------------- LayerNorm: wave per row; optional bf16 copy ----------------
__global__ __launch_bounds__(256) void k_ln(const float* __restrict__ P,
    const float* __restrict__ g, const float* __restrict__ b,
    float* __restrict__ outF, bf16* __restrict__ outB) {
    int row = blockIdx.x * 4 + (threadIdx.x >> 6);
    int lane = threadIdx.x & 63;
    const float* p = P + (size_t)row * DMODEL + lane * 8;
    float4 a = *(const float4*)p;
    float4 c = *(const float4*)(p + 4);
    float s = a.x + a.y + a.z + a.w + c.x + c.y + c.z + c.w;
    #pragma unroll
    for (int off = 32; off > 0; off >>= 1) s += __shfl_xor(s, off, 64);
    float mean = s * (1.f / DMODEL);
    float d[8] = {a.x - mean, a.y - mean, a.z - mean, a.w - mean,
                  c.x - mean, c.y - mean, c.z - mean, c.w - mean};
    float vs = 0.f;
    #pragma unroll
    for (int j = 0; j < 8; ++j) vs += d[j] * d[j];
    #pragma unroll
    for (int off = 32; off > 0; off >>= 1) vs += __shfl_xor(vs, off, 64);
    float rstd = rsqrtf(vs * (1.f / DMODEL) + 1e-5f);
    float4 g0 = *(const float4*)(g + lane * 8);
    float4 g1 = *(const float4*)(g + lane * 8 + 4);
    float4 b0 = *(const float4*)(b + lane * 8);
    float4 b1 = *(const float4*)(b + lane * 8 + 4);
    float o[8] = {d[0] * rstd * g0.x + b0.x, d[1] * rstd * g0.y + b0.y,
                  d[2] * rstd * g0.z + b0.z, d[3] * rstd * g0.w + b0.w,
                  d[4] * rstd * g1.x + b1.x, d[5] * rstd * g1.y + b1.y,
                  d[6] * rstd * g1.z + b1.z, d[7] * rstd * g1.w + b1.w};
    float* of = outF + (size_t)row * DMODEL + lane * 8;
    *(float4*)of       = make_float4(o[0], o[1], o[2], o[3]);
    *(float4*)(of + 4) = make_float4(o[4], o[5], o[6], o[7]);
    if (outB) {
        bf16* ob = outB + (size_t)row * DMODEL + lane * 8;
        #pragma unroll
        for (int j = 0; j < 8; ++j) ob[j] = f2bf(o[j]);
    }
}

extern "C" void kernel_launch(void* const* d_in, const int* in_sizes, int n_in,
                              void* d_out, int out_size, void* d_ws, size_t ws_size,
                              hipStream_t stream) {
    const int*   src  = (const int*)d_in[0];
    const int*   mask = (const int*)d_in[1];
    const float* emb  = (const float*)d_in[2];
    const float* Wq   = (const float*)d_in[3];
    const float* bq   = (const float*)d_in[4];
    const float* Wk   = (const float*)d_in[5];
    const float* bk   = (const float*)d_in[6];
    const float* Wv   = (const float*)d_in[7];
    const float* bv   = (const float*)d_in[8];
    const float* Wo   = (const float*)d_in[9];
    const float* bo   = (const float*)d_in[10];
    const float* W1   = (const float*)d_in[11];
    const float* b1   = (const float*)d_in[12];
    const float* W2   = (const float*)d_in[13];
    const float* b2   = (const float*)d_in[14];
    const float* ln1g = (const float*)d_in[15];
    const float* ln1b = (const float*)d_in[16];
    const float* ln2g = (const float*)d_in[17];
    const float* ln2b = (const float*)d_in[18];

    const size_t NSD = (size_t)NS_TOK * DMODEL;
    float* h  = (float*)d_ws;            // 8.39 MB
    float* hb_f = h + NSD;               // reuse slot: hb bf16 (4.19 MB as 1M floats)
    bf16*  hb = (bf16*)hb_f;
    float* P  = hb_f + NSD / 2;          // 8.39 MB
    bf16*  Qb = (bf16*)(P + NSD);        // 4x 4.19 MB
    bf16*  Kb = Qb + NSD;
    bf16*  Vb = Kb + NSD;
    bf16*  Ab = Vb + NSD;
    bf16*  F1b = Qb;                     // aliases Qb..Ab (16.78 MB), disjoint lifetime

    k_embed<<<NS_TOK, 256, 0, stream>>>(src, emb, h);
    for (int l = 0; l < 6; ++l) {
        k_qkv<<<NS_TOK / 4, 256, 0, stream>>>(h,
            Wq + (size_t)l * HDIM * HDIM, bq + l * HDIM,
            Wk + (size_t)l * HDIM * HDIM, bk + l * HDIM,
            Wv + (size_t)l * HDIM * HDIM, bv + l * HDIM,
            Qb, Kb, Vb);
        k_attn<<<dim3(SEQ / 32, NHEAD, NB), 256, 0, stream>>>(Qb, Kb, Vb, mask, Ab);
        // oproj: P = Ab @ Wo^T + bo + h
        k_gemm<64, false><<<dim3(NS_TOK / 64, DMODEL / 128), 256, 0, stream>>>(
            Ab, Wo + (size_t)l * DMODEL * DMODEL, bo + l * DMODEL,
            DMODEL, DMODEL, h, P, nullptr);
        // LN1 -> h (f32) + hb (bf16)
        k_ln<<<NS_TOK / 4, 256, 0, stream>>>(P, ln1g + l * DMODEL, ln1b + l * DMODEL, h, hb);
        // FFN1: F1b = relu(hb @ W1^T + b1)
        k_gemm<128, true><<<dim3(NS_TOK / 128, FFDIM / 128), 256, 0, stream>>>(
            hb, W1 + (size_t)l * FFDIM * DMODEL, b1 + l * FFDIM,
            DMODEL, FFDIM, nullptr, nullptr, F1b);
        // FFN2: P = F1b @ W2^T + b2 + h
        k_gemm<64, false><<<dim3(NS_TOK / 64, DMODEL / 128), 256, 0, stream>>>(
            F1b, W2 + (size_t)l * DMODEL * FFDIM, b2 + l * DMODEL,
            FFDIM, DMODEL, h, P, nullptr);
        // LN2 -> h (or d_out at final layer)
        float* lnout = (l == 5) ? (float*)d_out : h;
        k_ln<<<NS_TOK / 4, 256, 0, stream>>>(P, ln2g + l * DMODEL, ln2b + l * DMODEL, lnout, nullptr);
    }
}

// Round 5
// 1692.512 us; speedup vs baseline: 5.5743x; 2.1820x over previous
//
#include <hip/hip_runtime.h>
#include <hip/hip_bf16.h>

// Encoder: L=6, D=512, H=8, HD=64, F=2048, V=32000, N=2, S=2048, NS=4096
// fp32 inputs/outputs. MFMA for FFN/oproj GEMMs and for attention (QK^T, PV).
// ws: h(8.39) | hb(4.19) | P(8.39) | Qb Kb Vt Ab (16.78, aliased by F1b) = 37.8 MB
// V is stored TRANSPOSED in global ws: Vt[(n*8+h)*64 + dim][key] (bf16).

#define NS_TOK 4096
#define DMODEL 512
#define NHEAD 8
#define HDIM 64
#define FFDIM 2048
#define SEQ 2048
#define NB 2

typedef __hip_bfloat16 bf16;
typedef __attribute__((ext_vector_type(8))) short short8;
typedef __attribute__((ext_vector_type(4))) float floatx4;

__device__ __forceinline__ float bf2f(bf16 x) { return __bfloat162float(x); }
__device__ __forceinline__ bf16 f2bf(float x) { return __float2bfloat16(x); }
__device__ __forceinline__ short bfbits(float x) {
    bf16 h = __float2bfloat16(x);
    return *reinterpret_cast<short*>(&h);
}

// ---------------- embed ----------------
__global__ __launch_bounds__(256) void k_embed(const int* __restrict__ src,
                                               const float* __restrict__ emb,
                                               float* __restrict__ h) {
    int row = blockIdx.x;
    int t = threadIdx.x;
    int tok = src[row];
    const float* e = emb + (size_t)tok * DMODEL;
    float* o = h + (size_t)row * DMODEL;
    o[t]       = e[t]       * 22.62741699796952f;
    o[t + 256] = e[t + 256] * 22.62741699796952f;
}

// ---------------- QKV projection; V written transposed [(n,h,dim)][key] --------
__global__ __launch_bounds__(256) void k_qkv(const float* __restrict__ h,
    const float* __restrict__ Wq, const float* __restrict__ bq,
    const float* __restrict__ Wk, const float* __restrict__ bk,
    const float* __restrict__ Wv, const float* __restrict__ bv,
    bf16* __restrict__ Qo, bf16* __restrict__ Ko, bf16* __restrict__ Vt) {
    __shared__ float x[4][DMODEL];
    int r0 = blockIdx.x * 4;
    int t = threadIdx.x;
    for (int j = t; j < 4 * DMODEL; j += 256) x[j >> 9][j & 511] = h[(size_t)r0 * DMODEL + j];
    __syncthreads();
    int n = r0 >> 11, s0 = r0 & 2047;
    const float* Ws[3] = {Wq, Wk, Wv};
    const float* Bs[3] = {bq, bk, bv};
    for (int tn = 0; tn < 3; ++tn) {
        const float* W = Ws[tn];
        for (int jo = 0; jo < 2; ++jo) {
            int o = t + jo * 256;
            int e = o & 63, hd = o >> 6;
            const float4* w4 = (const float4*)(W + e * HDIM);
            float a0 = 0.f, a1 = 0.f, a2 = 0.f, a3 = 0.f;
            #pragma unroll
            for (int j = 0; j < 16; ++j) {
                float4 wv = w4[j];
                int d = hd * HDIM + j * 4;
                float4 x0 = *(const float4*)&x[0][d];
                float4 x1 = *(const float4*)&x[1][d];
                float4 x2 = *(const float4*)&x[2][d];
                float4 x3 = *(const float4*)&x[3][d];
                a0 += x0.x * wv.x + x0.y * wv.y + x0.z * wv.z + x0.w * wv.w;
                a1 += x1.x * wv.x + x1.y * wv.y + x1.z * wv.z + x1.w * wv.w;
                a2 += x2.x * wv.x + x2.y * wv.y + x2.z * wv.z + x2.w * wv.w;
                a3 += x3.x * wv.x + x3.y * wv.y + x3.z * wv.z + x3.w * wv.w;
            }
            float bias = Bs[tn][e];
            if (tn < 2) {
                bf16* O = (tn == 0) ? Qo : Ko;
                O[(size_t)(r0 + 0) * DMODEL + o] = f2bf(a0 + bias);
                O[(size_t)(r0 + 1) * DMODEL + o] = f2bf(a1 + bias);
                O[(size_t)(r0 + 2) * DMODEL + o] = f2bf(a2 + bias);
                O[(size_t)(r0 + 3) * DMODEL + o] = f2bf(a3 + bias);
            } else {
                short4 pk;
                pk.x = bfbits(a0 + bias); pk.y = bfbits(a1 + bias);
                pk.z = bfbits(a2 + bias); pk.w = bfbits(a3 + bias);
                *(short4*)(Vt + ((size_t)((n * NHEAD + hd) * HDIM + e)) * SEQ + s0) = pk;
            }
        }
    }
}

// ---------------- MFMA flash attention: 64-q tile, 64-k tiles, online softmax ---
// 4 waves; wave w owns queries w*16..+16. S and PV via 16x16x32 bf16 MFMA.
// Frag conventions (empirically verified by k_gemm): A[m=lane&15][k=quad*8+j],
// B[n=lane&15][k=quad*8+j], D row=quad*4+r, col=lane&15.
__global__ __launch_bounds__(256) void k_attn(const bf16* __restrict__ Qb,
                                              const bf16* __restrict__ Kb,
                                              const bf16* __restrict__ Vt,
                                              const int* __restrict__ mask,
                                              bf16* __restrict__ Ab) {
    __shared__ short Qs[64 * 72];
    __shared__ short Ks[64 * 72];
    __shared__ short Vs[64 * 72];     // [dim][key], from transposed global V
    __shared__ short Ps[4][16 * 72];  // per-wave P slab [query][key]
    int t = threadIdx.x, lane = t & 63, w = t >> 6;
    int l15 = lane & 15, quad = lane >> 4;
    int q0 = blockIdx.x * 64, hh = blockIdx.y, n = blockIdx.z;
    const float SCALE = 0.044194173824159216f;  // 1/sqrt(512)
    size_t tokbase = (size_t)n * SEQ;
    size_t vbase = ((size_t)(n * NHEAD + hh) * HDIM) * SEQ;

    #pragma unroll
    for (int i = 0; i < 2; ++i) {   // stage Q tile (64 x 64 bf16)
        int idx = t + 256 * i;
        int row = idx >> 3, q = idx & 7;
        *(uint4*)&Qs[row * 72 + q * 8] =
            *(const uint4*)(Qb + (tokbase + q0 + row) * DMODEL + hh * HDIM + q * 8);
    }
    __syncthreads();
    short8 aq[2];
    aq[0] = *(short8*)&Qs[(w * 16 + l15) * 72 + quad * 8];
    aq[1] = *(short8*)&Qs[(w * 16 + l15) * 72 + 32 + quad * 8];

    floatx4 accO[4];
    float mold[4], lsum[4];
    #pragma unroll
    for (int fn = 0; fn < 4; ++fn)
        #pragma unroll
        for (int r = 0; r < 4; ++r) accO[fn][r] = 0.f;
    #pragma unroll
    for (int r = 0; r < 4; ++r) { mold[r] = -3.0e38f; lsum[r] = 0.f; }

    for (int k0 = 0; k0 < SEQ; k0 += 64) {
        __syncthreads();
        #pragma unroll
        for (int i = 0; i < 2; ++i) {   // stage K (token-major) and V^T (dim-major)
            int idx = t + 256 * i;
            int row = idx >> 3, q = idx & 7;
            *(uint4*)&Ks[row * 72 + q * 8] =
                *(const uint4*)(Kb + (tokbase + k0 + row) * DMODEL + hh * HDIM + q * 8);
            *(uint4*)&Vs[row * 72 + q * 8] =
                *(const uint4*)(Vt + vbase + (size_t)row * SEQ + k0 + q * 8);
        }
        __syncthreads();
        // S = Q K^T for this wave's 16 queries x 64 keys
        floatx4 accS[4];
        #pragma unroll
        for (int fj = 0; fj < 4; ++fj)
            #pragma unroll
            for (int r = 0; r < 4; ++r) accS[fj][r] = 0.f;
        #pragma unroll
        for (int ks = 0; ks < 2; ++ks)
            #pragma unroll
            for (int fj = 0; fj < 4; ++fj) {
                short8 bk = *(short8*)&Ks[(fj * 16 + l15) * 72 + ks * 32 + quad * 8];
                accS[fj] = __builtin_amdgcn_mfma_f32_16x16x32_bf16(aq[ks], bk, accS[fj], 0, 0, 0);
            }
        // mask + scale
        #pragma unroll
        for (int fj = 0; fj < 4; ++fj) {
            int mk = mask[n * SEQ + k0 + fj * 16 + l15];
            #pragma unroll
            for (int r = 0; r < 4; ++r)
                accS[fj][r] = mk ? accS[fj][r] * SCALE : -4.4194e8f;
        }
        // online softmax per query row (rows live in quad-group of 16 lanes)
        float al[4];
        #pragma unroll
        for (int r = 0; r < 4; ++r) {
            float mx = fmaxf(fmaxf(accS[0][r], accS[1][r]), fmaxf(accS[2][r], accS[3][r]));
            mx = fmaxf(mx, __shfl_xor(mx, 1, 64));
            mx = fmaxf(mx, __shfl_xor(mx, 2, 64));
            mx = fmaxf(mx, __shfl_xor(mx, 4, 64));
            mx = fmaxf(mx, __shfl_xor(mx, 8, 64));
            float mn = fmaxf(mold[r], mx);
            al[r] = __expf(mold[r] - mn);
            mold[r] = mn;
            float s = 0.f;
            #pragma unroll
            for (int fj = 0; fj < 4; ++fj) {
                float p = __expf(accS[fj][r] - mn);
                s += p;
                Ps[w][(quad * 4 + r) * 72 + fj * 16 + l15] = bfbits(p);
            }
            s += __shfl_xor(s, 1, 64);
            s += __shfl_xor(s, 2, 64);
            s += __shfl_xor(s, 4, 64);
            s += __shfl_xor(s, 8, 64);
            lsum[r] = lsum[r] * al[r] + s;
        }
        #pragma unroll
        for (int fn = 0; fn < 4; ++fn)
            #pragma unroll
            for (int r = 0; r < 4; ++r) accO[fn][r] *= al[r];
        // O += P V  (A = P from per-wave slab, B = V^T rows = dims)
        #pragma unroll
        for (int ks = 0; ks < 2; ++ks) {
            short8 ap = *(short8*)&Ps[w][l15 * 72 + ks * 32 + quad * 8];
            #pragma unroll
            for (int fn = 0; fn < 4; ++fn) {
                short8 bv = *(short8*)&Vs[(fn * 16 + l15) * 72 + ks * 32 + quad * 8];
                accO[fn] = __builtin_amdgcn_mfma_f32_16x16x32_bf16(ap, bv, accO[fn], 0, 0, 0);
            }
        }
    }
    // epilogue: D row = query = quad*4+r, col = dim = fn*16 + l15
    #pragma unroll
    for (int r = 0; r < 4; ++r) {
        float inv = 1.f / lsum[r];
        int row = q0 + w * 16 + quad * 4 + r;
        bf16* dst = Ab + (tokbase + row) * DMODEL + hh * HDIM;
        #pragma unroll
        for (int fn = 0; fn < 4; ++fn)
            dst[fn * 16 + l15] = f2bf(accO[fn][r] * inv);
    }
}

// ---------------- MFMA GEMM: C[M,N] = A[M,K](bf16) @ W[N,K](f32->bf16)^T --------
template<int MT, bool RELU>
__global__ __launch_bounds__(256) void k_gemm(const bf16* __restrict__ A,
    const float* __restrict__ W, const float* __restrict__ bias, int K, int N,
    const float* __restrict__ resid, float* __restrict__ outF, bf16* __restrict__ outB) {
    constexpr int FI = 4;
    constexpr int FJ = (MT == 128) ? 4 : 2;
    __shared__ short As[MT * 40];
    __shared__ short Bs[128 * 40];
    int t = threadIdx.x, lane = t & 63, w = t >> 6;
    int m0 = blockIdx.x * MT, n0 = blockIdx.y * 128;
    int wrow = (MT == 128) ? (w >> 1) * 64 : 0;
    int wcol = (MT == 128) ? (w & 1) * 64 : w * 32;
    int quad = lane >> 4, mrow = lane & 15;
    floatx4 acc[FI][FJ];
    #pragma unroll
    for (int fi = 0; fi < FI; ++fi)
        #pragma unroll
        for (int fj = 0; fj < FJ; ++fj)
            #pragma unroll
            for (int r = 0; r < 4; ++r) acc[fi][fj][r] = 0.f;

    for (int k0 = 0; k0 < K; k0 += 32) {
        __syncthreads();
        #pragma unroll
        for (int i = 0; i < MT / 64; ++i) {      // A tile: MT x 32 bf16
            int idx = t + i * 256;
            int row = idx >> 2, q = idx & 3;
            uint4 u = *(const uint4*)(A + (size_t)(m0 + row) * K + k0 + q * 8);
            *(uint4*)&As[row * 40 + q * 8] = u;
        }
        #pragma unroll
        for (int i = 0; i < 2; ++i) {            // W tile: 128 x 32 f32 -> bf16
            int idx = t + i * 256;
            int row = idx >> 2, q = idx & 3;
            const float* src = W + (size_t)(n0 + row) * K + k0 + q * 8;
            float4 f0 = *(const float4*)src;
            float4 f1 = *(const float4*)(src + 4);
            short8 sv;
            sv[0] = bfbits(f0.x); sv[1] = bfbits(f0.y);
            sv[2] = bfbits(f0.z); sv[3] = bfbits(f0.w);
            sv[4] = bfbits(f1.x); sv[5] = bfbits(f1.y);
            sv[6] = bfbits(f1.z); sv[7] = bfbits(f1.w);
            *(short8*)&Bs[row * 40 + q * 8] = sv;
        }
        __syncthreads();
        short8 af[FI], bfr[FJ];
        #pragma unroll
        for (int fi = 0; fi < FI; ++fi)
            af[fi] = *(short8*)&As[(wrow + fi * 16 + mrow) * 40 + quad * 8];
        #pragma unroll
        for (int fj = 0; fj < FJ; ++fj)
            bfr[fj] = *(short8*)&Bs[(wcol + fj * 16 + mrow) * 40 + quad * 8];
        #pragma unroll
        for (int fi = 0; fi < FI; ++fi)
            #pragma unroll
            for (int fj = 0; fj < FJ; ++fj)
                acc[fi][fj] = __builtin_amdgcn_mfma_f32_16x16x32_bf16(
                    af[fi], bfr[fj], acc[fi][fj], 0, 0, 0);
    }
    #pragma unroll
    for (int fi = 0; fi < FI; ++fi)
        #pragma unroll
        for (int fj = 0; fj < FJ; ++fj) {
            int col = n0 + wcol + fj * 16 + mrow;
            float bv = bias[col];
            #pragma unroll
            for (int r = 0; r < 4; ++r) {
                int row = m0 + wrow + fi * 16 + quad * 4 + r;
                float v = acc[fi][fj][r] + bv;
                if (RELU) {
                    outB[(size_t)row * N + col] = f2bf(fmaxf(v, 0.f));
                } else {
                    outF[(size_t)row * N + col] = v + resid[(size_t)row * N + col];
                }
            }
        }
}

// ---------------- LayerNorm: wave per row; optional bf16 copy ----------------
__global__ __launch_bounds__(256) void k_ln(const float* __restrict__ P,
    const float* __restrict__ g, const float* __restrict__ b,
    float* __restrict__ outF, bf16* __restrict__ outB) {
    int row = blockIdx.x * 4 + (threadIdx.x >> 6);
    int lane = threadIdx.x & 63;
    const float* p = P + (size_t)row * DMODEL + lane * 8;
    float4 a = *(const float4*)p;
    float4 c = *(const float4*)(p + 4);
    float s = a.x + a.y + a.z + a.w + c.x + c.y + c.z + c.w;
    #pragma unroll
    for (int off = 32; off > 0; off >>= 1) s += __shfl_xor(s, off, 64);
    float mean = s * (1.f / DMODEL);
    float d[8] = {a.x - mean, a.y - mean, a.z - mean, a.w - mean,
                  c.x - mean, c.y - mean, c.z - mean, c.w - mean};
    float vs = 0.f;
    #pragma unroll
    for (int j = 0; j < 8; ++j) vs += d[j] * d[j];
    #pragma unroll
    for (int off = 32; off > 0; off >>= 1) vs += __shfl_xor(vs, off, 64);
    float rstd = rsqrtf(vs * (1.f / DMODEL) + 1e-5f);
    float4 g0 = *(const float4*)(g + lane * 8);
    float4 g1 = *(const float4*)(g + lane * 8 + 4);
    float4 b0 = *(const float4*)(b + lane * 8);
    float4 b1 = *(const float4*)(b + lane * 8 + 4);
    float o[8] = {d[0] * rstd * g0.x + b0.x, d[1] * rstd * g0.y + b0.y,
                  d[2] * rstd * g0.z + b0.z, d[3] * rstd * g0.w + b0.w,
                  d[4] * rstd * g1.x + b1.x, d[5] * rstd * g1.y + b1.y,
                  d[6] * rstd * g1.z + b1.z, d[7] * rstd * g1.w + b1.w};
    float* of = outF + (size_t)row * DMODEL + lane * 8;
    *(float4*)of       = make_float4(o[0], o[1], o[2], o[3]);
    *(float4*)(of + 4) = make_float4(o[4], o[5], o[6], o[7]);
    if (outB) {
        bf16* ob = outB + (size_t)row * DMODEL + lane * 8;
        #pragma unroll
        for (int j = 0; j < 8; ++j) ob[j] = f2bf(o[j]);
    }
}

extern "C" void kernel_launch(void* const* d_in, const int* in_sizes, int n_in,
                              void* d_out, int out_size, void* d_ws, size_t ws_size,
                              hipStream_t stream) {
    const int*   src  = (const int*)d_in[0];
    const int*   mask = (const int*)d_in[1];
    const float* emb  = (const float*)d_in[2];
    const float* Wq   = (const float*)d_in[3];
    const float* bq   = (const float*)d_in[4];
    const float* Wk   = (const float*)d_in[5];
    const float* bk   = (const float*)d_in[6];
    const float* Wv   = (const float*)d_in[7];
    const float* bv   = (const float*)d_in[8];
    const float* Wo   = (const float*)d_in[9];
    const float* bo   = (const float*)d_in[10];
    const float* W1   = (const float*)d_in[11];
    const float* b1   = (const float*)d_in[12];
    const float* W2   = (const float*)d_in[13];
    const float* b2   = (const float*)d_in[14];
    const float* ln1g = (const float*)d_in[15];
    const float* ln1b = (const float*)d_in[16];
    const float* ln2g = (const float*)d_in[17];
    const float* ln2b = (const float*)d_in[18];

    const size_t NSD = (size_t)NS_TOK * DMODEL;
    float* h  = (float*)d_ws;            // 8.39 MB
    float* hb_f = h + NSD;
    bf16*  hb = (bf16*)hb_f;             // 4.19 MB
    float* P  = hb_f + NSD / 2;          // 8.39 MB
    bf16*  Qb = (bf16*)(P + NSD);        // 4x 4.19 MB
    bf16*  Kb = Qb + NSD;
    bf16*  Vt = Kb + NSD;                // transposed V [(n,h,dim)][key]
    bf16*  Ab = Vt + NSD;
    bf16*  F1b = Qb;                     // aliases Qb..Ab, disjoint lifetime

    k_embed<<<NS_TOK, 256, 0, stream>>>(src, emb, h);
    for (int l = 0; l < 6; ++l) {
        k_qkv<<<NS_TOK / 4, 256, 0, stream>>>(h,
            Wq + (size_t)l * HDIM * HDIM, bq + l * HDIM,
            Wk + (size_t)l * HDIM * HDIM, bk + l * HDIM,
            Wv + (size_t)l * HDIM * HDIM, bv + l * HDIM,
            Qb, Kb, Vt);
        k_attn<<<dim3(SEQ / 64, NHEAD, NB), 256, 0, stream>>>(Qb, Kb, Vt, mask, Ab);
        k_gemm<64, false><<<dim3(NS_TOK / 64, DMODEL / 128), 256, 0, stream>>>(
            Ab, Wo + (size_t)l * DMODEL * DMODEL, bo + l * DMODEL,
            DMODEL, DMODEL, h, P, nullptr);
        k_ln<<<NS_TOK / 4, 256, 0, stream>>>(P, ln1g + l * DMODEL, ln1b + l * DMODEL, h, hb);
        k_gemm<128, true><<<dim3(NS_TOK / 128, FFDIM / 128), 256, 0, stream>>>(
            hb, W1 + (size_t)l * FFDIM * DMODEL, b1 + l * FFDIM,
            DMODEL, FFDIM, nullptr, nullptr, F1b);
        k_gemm<64, false><<<dim3(NS_TOK / 64, DMODEL / 128), 256, 0, stream>>>(
            F1b, W2 + (size_t)l * DMODEL * FFDIM, b2 + l * DMODEL,
            FFDIM, DMODEL, h, P, nullptr);
        float* lnout = (l == 5) ? (float*)d_out : h;
        k_ln<<<NS_TOK / 4, 256, 0, stream>>>(P, ln2g + l * DMODEL, ln2b + l * DMODEL, lnout, nullptr);
    }
}

// Round 6
// 1332.506 us; speedup vs baseline: 7.0804x; 1.2702x over previous
//
#include <hip/hip_runtime.h>
#include <hip/hip_bf16.h>

// Encoder: L=6, D=512, H=8, HD=64, F=2048, V=32000, N=2, S=2048, NS=4096
// fp32 inputs/outputs. MFMA everywhere (qkv, attention, oproj, ffn).
// Split-K(2) flash attention with combine pass; softmax in exp2 domain.
// ws: h(8.39) | hb(4.19, also m/l scratch) | P(8.39, also attn partials) |
//     Qb Kb Vt Ab (16.78, aliased by F1b) = 37.8 MB

#define NS_TOK 4096
#define DMODEL 512
#define NHEAD 8
#define HDIM 64
#define FFDIM 2048
#define SEQ 2048
#define NB 2

typedef __hip_bfloat16 bf16;
typedef __attribute__((ext_vector_type(8))) short short8;
typedef __attribute__((ext_vector_type(4))) float floatx4;

__device__ __forceinline__ float bf2f(bf16 x) { return __bfloat162float(x); }
__device__ __forceinline__ bf16 f2bf(float x) { return __float2bfloat16(x); }
__device__ __forceinline__ short bfbits(float x) {
    bf16 h = __float2bfloat16(x);
    return *reinterpret_cast<short*>(&h);
}
__device__ __forceinline__ float2 bf2x2(unsigned int u) {
    float2 r;
    r.x = __uint_as_float(u << 16);
    r.y = __uint_as_float(u & 0xffff0000u);
    return r;
}

// ---------------- embed: h fp32 + hb bf16 ----------------
__global__ __launch_bounds__(256) void k_embed(const int* __restrict__ src,
                                               const float* __restrict__ emb,
                                               float* __restrict__ h,
                                               bf16* __restrict__ hb) {
    int row = blockIdx.x;
    int t = threadIdx.x;
    int tok = src[row];
    const float* e = emb + (size_t)tok * DMODEL;
    float v0 = e[t] * 22.62741699796952f;
    float v1 = e[t + 256] * 22.62741699796952f;
    h[(size_t)row * DMODEL + t] = v0;
    h[(size_t)row * DMODEL + t + 256] = v1;
    hb[(size_t)row * DMODEL + t] = f2bf(v0);
    hb[(size_t)row * DMODEL + t + 256] = f2bf(v1);
}

// ---------------- QKV via MFMA: block = (64-token tile, head) ----------------
// A = hb[tok][hh*64+d] bf16; B = W[e][d] (shared across heads) fp32->bf16.
// Q,K token-major; V transposed [(n,h,dim)][key].
__global__ __launch_bounds__(256) void k_qkv(const bf16* __restrict__ hb,
    const float* __restrict__ Wq, const float* __restrict__ bq,
    const float* __restrict__ Wk, const float* __restrict__ bk,
    const float* __restrict__ Wv, const float* __restrict__ bv,
    bf16* __restrict__ Qo, bf16* __restrict__ Ko, bf16* __restrict__ Vt) {
    __shared__ short Xs[64 * 72];
    __shared__ short Ws3[3][64 * 72];
    int t = threadIdx.x, lane = t & 63, w = t >> 6;
    int l15 = lane & 15, quad = lane >> 4;
    int tok0 = blockIdx.x * 64, hh = blockIdx.y;
    int n = tok0 >> 11, s0loc = tok0 & 2047;
    const float* Ws[3] = {Wq, Wk, Wv};
    const float* Bs[3] = {bq, bk, bv};

    #pragma unroll
    for (int i = 0; i < 2; ++i) {   // stage X: 64 tok x 64 dims
        int idx = t + i * 256;
        int row = idx >> 3, g = idx & 7;
        *(uint4*)&Xs[row * 72 + g * 8] =
            *(const uint4*)(hb + (size_t)(tok0 + row) * DMODEL + hh * HDIM + g * 8);
    }
    #pragma unroll
    for (int tn = 0; tn < 3; ++tn)  // stage W: 3 x 64x64 fp32 -> bf16
        #pragma unroll
        for (int i = 0; i < 2; ++i) {
            int idx = t + i * 256;
            int row = idx >> 3, g = idx & 7;
            const float* srcp = Ws[tn] + row * HDIM + g * 8;
            float4 f0 = *(const float4*)srcp;
            float4 f1 = *(const float4*)(srcp + 4);
            short8 sv;
            sv[0] = bfbits(f0.x); sv[1] = bfbits(f0.y);
            sv[2] = bfbits(f0.z); sv[3] = bfbits(f0.w);
            sv[4] = bfbits(f1.x); sv[5] = bfbits(f1.y);
            sv[6] = bfbits(f1.z); sv[7] = bfbits(f1.w);
            *(short8*)&Ws3[tn][row * 72 + g * 8] = sv;
        }
    __syncthreads();
    short8 aq[2];
    aq[0] = *(short8*)&Xs[(w * 16 + l15) * 72 + quad * 8];
    aq[1] = *(short8*)&Xs[(w * 16 + l15) * 72 + 32 + quad * 8];

    #pragma unroll
    for (int tn = 0; tn < 3; ++tn) {
        floatx4 acc[4];
        #pragma unroll
        for (int fj = 0; fj < 4; ++fj)
            #pragma unroll
            for (int r = 0; r < 4; ++r) acc[fj][r] = 0.f;
        #pragma unroll
        for (int ks = 0; ks < 2; ++ks)
            #pragma unroll
            for (int fj = 0; fj < 4; ++fj) {
                short8 bfrag = *(short8*)&Ws3[tn][(fj * 16 + l15) * 72 + ks * 32 + quad * 8];
                acc[fj] = __builtin_amdgcn_mfma_f32_16x16x32_bf16(aq[ks], bfrag, acc[fj], 0, 0, 0);
            }
        #pragma unroll
        for (int fj = 0; fj < 4; ++fj) {
            int col = fj * 16 + l15;
            float bias = Bs[tn][col];
            if (tn < 2) {
                bf16* O = (tn == 0) ? Qo : Ko;
                #pragma unroll
                for (int r = 0; r < 4; ++r) {
                    int tok = tok0 + w * 16 + quad * 4 + r;
                    O[(size_t)tok * DMODEL + hh * HDIM + col] = f2bf(acc[fj][r] + bias);
                }
            } else {
                short4 pk;
                pk.x = bfbits(acc[fj][0] + bias); pk.y = bfbits(acc[fj][1] + bias);
                pk.z = bfbits(acc[fj][2] + bias); pk.w = bfbits(acc[fj][3] + bias);
                int sl = s0loc + w * 16 + quad * 4;
                *(short4*)(Vt + ((size_t)((n * NHEAD + hh) * HDIM + col)) * SEQ + sl) = pk;
            }
        }
    }
}

// ---------------- MFMA flash attention, split-K(2), exp2-domain softmax --------
// grid (32, 8, 4): z = n*2+split. Each block: 64 queries x 1024 keys.
// Writes unnormalized O (bf16) + per-(tok,head) m,l (log2 domain).
__global__ __launch_bounds__(256) void k_attn(const bf16* __restrict__ Qb,
                                              const bf16* __restrict__ Kb,
                                              const bf16* __restrict__ Vt,
                                              const int* __restrict__ mask,
                                              bf16* __restrict__ Po,
                                              float* __restrict__ Mm,
                                              float* __restrict__ Ll) {
    __shared__ short Qs[64 * 72];
    __shared__ short Ks[64 * 72];
    __shared__ short Vs[64 * 72];
    __shared__ short Ps[4][16 * 72];
    int t = threadIdx.x, lane = t & 63, w = t >> 6;
    int l15 = lane & 15, quad = lane >> 4;
    int q0 = blockIdx.x * 64, hh = blockIdx.y;
    int n = blockIdx.z >> 1, sp = blockIdx.z & 1;
    const float SCALE2 = 0.044194173824159216f * 1.44269504088896341f;  // /sqrt(512)*log2e
    size_t tokbase = (size_t)n * SEQ;
    size_t vbase = ((size_t)(n * NHEAD + hh) * HDIM) * SEQ;

    #pragma unroll
    for (int i = 0; i < 2; ++i) {
        int idx = t + 256 * i;
        int row = idx >> 3, q = idx & 7;
        *(uint4*)&Qs[row * 72 + q * 8] =
            *(const uint4*)(Qb + (tokbase + q0 + row) * DMODEL + hh * HDIM + q * 8);
    }
    __syncthreads();
    short8 aq[2];
    aq[0] = *(short8*)&Qs[(w * 16 + l15) * 72 + quad * 8];
    aq[1] = *(short8*)&Qs[(w * 16 + l15) * 72 + 32 + quad * 8];

    floatx4 accO[4];
    float mold[4], lsum[4];
    #pragma unroll
    for (int fn = 0; fn < 4; ++fn)
        #pragma unroll
        for (int r = 0; r < 4; ++r) accO[fn][r] = 0.f;
    #pragma unroll
    for (int r = 0; r < 4; ++r) { mold[r] = -1.0e38f; lsum[r] = 0.f; }

    int kbeg = sp * (SEQ / 2), kend = kbeg + SEQ / 2;
    for (int k0 = kbeg; k0 < kend; k0 += 64) {
        __syncthreads();
        #pragma unroll
        for (int i = 0; i < 2; ++i) {
            int idx = t + 256 * i;
            int row = idx >> 3, q = idx & 7;
            *(uint4*)&Ks[row * 72 + q * 8] =
                *(const uint4*)(Kb + (tokbase + k0 + row) * DMODEL + hh * HDIM + q * 8);
            *(uint4*)&Vs[row * 72 + q * 8] =
                *(const uint4*)(Vt + vbase + (size_t)row * SEQ + k0 + q * 8);
        }
        __syncthreads();
        floatx4 accS[4];
        #pragma unroll
        for (int fj = 0; fj < 4; ++fj)
            #pragma unroll
            for (int r = 0; r < 4; ++r) accS[fj][r] = 0.f;
        #pragma unroll
        for (int ks = 0; ks < 2; ++ks)
            #pragma unroll
            for (int fj = 0; fj < 4; ++fj) {
                short8 bk = *(short8*)&Ks[(fj * 16 + l15) * 72 + ks * 32 + quad * 8];
                accS[fj] = __builtin_amdgcn_mfma_f32_16x16x32_bf16(aq[ks], bk, accS[fj], 0, 0, 0);
            }
        #pragma unroll
        for (int fj = 0; fj < 4; ++fj) {
            int mk = mask[n * SEQ + k0 + fj * 16 + l15];
            #pragma unroll
            for (int r = 0; r < 4; ++r)
                accS[fj][r] = mk ? accS[fj][r] * SCALE2 : -1.0e9f;
        }
        float al[4];
        #pragma unroll
        for (int r = 0; r < 4; ++r) {
            float mx = fmaxf(fmaxf(accS[0][r], accS[1][r]), fmaxf(accS[2][r], accS[3][r]));
            mx = fmaxf(mx, __shfl_xor(mx, 1, 64));
            mx = fmaxf(mx, __shfl_xor(mx, 2, 64));
            mx = fmaxf(mx, __shfl_xor(mx, 4, 64));
            mx = fmaxf(mx, __shfl_xor(mx, 8, 64));
            float mn = fmaxf(mold[r], mx);
            al[r] = exp2f(mold[r] - mn);
            mold[r] = mn;
            float s = 0.f;
            #pragma unroll
            for (int fj = 0; fj < 4; ++fj) {
                float p = exp2f(accS[fj][r] - mn);
                s += p;
                Ps[w][(quad * 4 + r) * 72 + fj * 16 + l15] = bfbits(p);
            }
            s += __shfl_xor(s, 1, 64);
            s += __shfl_xor(s, 2, 64);
            s += __shfl_xor(s, 4, 64);
            s += __shfl_xor(s, 8, 64);
            lsum[r] = lsum[r] * al[r] + s;
        }
        #pragma unroll
        for (int fn = 0; fn < 4; ++fn)
            #pragma unroll
            for (int r = 0; r < 4; ++r) accO[fn][r] *= al[r];
        #pragma unroll
        for (int ks = 0; ks < 2; ++ks) {
            short8 ap = *(short8*)&Ps[w][l15 * 72 + ks * 32 + quad * 8];
            #pragma unroll
            for (int fn = 0; fn < 4; ++fn) {
                short8 bv = *(short8*)&Vs[(fn * 16 + l15) * 72 + ks * 32 + quad * 8];
                accO[fn] = __builtin_amdgcn_mfma_f32_16x16x32_bf16(ap, bv, accO[fn], 0, 0, 0);
            }
        }
    }
    // epilogue: unnormalized O + (m, l)
    #pragma unroll
    for (int r = 0; r < 4; ++r) {
        int row = q0 + w * 16 + quad * 4 + r;            // seq-local
        size_t gtok = tokbase + row;
        bf16* dst = Po + ((size_t)sp * NS_TOK + gtok) * DMODEL + hh * HDIM;
        #pragma unroll
        for (int fn = 0; fn < 4; ++fn)
            dst[fn * 16 + l15] = f2bf(accO[fn][r]);
        if (l15 == 0) {
            Mm[((size_t)sp * NS_TOK + gtok) * NHEAD + hh] = mold[r];
            Ll[((size_t)sp * NS_TOK + gtok) * NHEAD + hh] = lsum[r];
        }
    }
}

// ---------------- combine the two K-splits ----------------
__global__ __launch_bounds__(256) void k_comb(const bf16* __restrict__ Po,
    const float* __restrict__ Mm, const float* __restrict__ Ll,
    bf16* __restrict__ Ab) {
    int tok = blockIdx.x * 4 + (threadIdx.x >> 6);
    int lane = threadIdx.x & 63;
    int hh = lane >> 3;   // 8 lanes per head (8 dims each)
    float m1 = Mm[(size_t)tok * NHEAD + hh];
    float m2 = Mm[((size_t)NS_TOK + tok) * NHEAD + hh];
    float l1 = Ll[(size_t)tok * NHEAD + hh];
    float l2 = Ll[((size_t)NS_TOK + tok) * NHEAD + hh];
    float m = fmaxf(m1, m2);
    float w1 = exp2f(m1 - m), w2 = exp2f(m2 - m);
    float inv = 1.f / (l1 * w1 + l2 * w2);
    uint4 u1 = *(const uint4*)(Po + (size_t)tok * DMODEL + lane * 8);
    uint4 u2 = *(const uint4*)(Po + ((size_t)NS_TOK + tok) * DMODEL + lane * 8);
    bf16* dst = Ab + (size_t)tok * DMODEL + lane * 8;
    const unsigned int* p1 = (const unsigned int*)&u1;
    const unsigned int* p2 = (const unsigned int*)&u2;
    #pragma unroll
    for (int j = 0; j < 4; ++j) {
        float2 a = bf2x2(p1[j]), b = bf2x2(p2[j]);
        dst[j * 2]     = f2bf((a.x * w1 + b.x * w2) * inv);
        dst[j * 2 + 1] = f2bf((a.y * w1 + b.y * w2) * inv);
    }
}

// ---------------- MFMA GEMM: C[M,N] = A[M,K](bf16) @ W[N,K](f32->bf16)^T --------
template<int MT, bool RELU>
__global__ __launch_bounds__(256) void k_gemm(const bf16* __restrict__ A,
    const float* __restrict__ W, const float* __restrict__ bias, int K, int N,
    const float* __restrict__ resid, float* __restrict__ outF, bf16* __restrict__ outB) {
    constexpr int FI = 4;
    constexpr int FJ = (MT == 128) ? 4 : 2;
    __shared__ short As[MT * 40];
    __shared__ short Bs[128 * 40];
    int t = threadIdx.x, lane = t & 63, w = t >> 6;
    int m0 = blockIdx.x * MT, n0 = blockIdx.y * 128;
    int wrow = (MT == 128) ? (w >> 1) * 64 : 0;
    int wcol = (MT == 128) ? (w & 1) * 64 : w * 32;
    int quad = lane >> 4, mrow = lane & 15;
    floatx4 acc[FI][FJ];
    #pragma unroll
    for (int fi = 0; fi < FI; ++fi)
        #pragma unroll
        for (int fj = 0; fj < FJ; ++fj)
            #pragma unroll
            for (int r = 0; r < 4; ++r) acc[fi][fj][r] = 0.f;

    for (int k0 = 0; k0 < K; k0 += 32) {
        __syncthreads();
        #pragma unroll
        for (int i = 0; i < MT / 64; ++i) {
            int idx = t + i * 256;
            int row = idx >> 2, q = idx & 3;
            uint4 u = *(const uint4*)(A + (size_t)(m0 + row) * K + k0 + q * 8);
            *(uint4*)&As[row * 40 + q * 8] = u;
        }
        #pragma unroll
        for (int i = 0; i < 2; ++i) {
            int idx = t + i * 256;
            int row = idx >> 2, q = idx & 3;
            const float* src = W + (size_t)(n0 + row) * K + k0 + q * 8;
            float4 f0 = *(const float4*)src;
            float4 f1 = *(const float4*)(src + 4);
            short8 sv;
            sv[0] = bfbits(f0.x); sv[1] = bfbits(f0.y);
            sv[2] = bfbits(f0.z); sv[3] = bfbits(f0.w);
            sv[4] = bfbits(f1.x); sv[5] = bfbits(f1.y);
            sv[6] = bfbits(f1.z); sv[7] = bfbits(f1.w);
            *(short8*)&Bs[row * 40 + q * 8] = sv;
        }
        __syncthreads();
        short8 af[FI], bfr[FJ];
        #pragma unroll
        for (int fi = 0; fi < FI; ++fi)
            af[fi] = *(short8*)&As[(wrow + fi * 16 + mrow) * 40 + quad * 8];
        #pragma unroll
        for (int fj = 0; fj < FJ; ++fj)
            bfr[fj] = *(short8*)&Bs[(wcol + fj * 16 + mrow) * 40 + quad * 8];
        #pragma unroll
        for (int fi = 0; fi < FI; ++fi)
            #pragma unroll
            for (int fj = 0; fj < FJ; ++fj)
                acc[fi][fj] = __builtin_amdgcn_mfma_f32_16x16x32_bf16(
                    af[fi], bfr[fj], acc[fi][fj], 0, 0, 0);
    }
    #pragma unroll
    for (int fi = 0; fi < FI; ++fi)
        #pragma unroll
        for (int fj = 0; fj < FJ; ++fj) {
            int col = n0 + wcol + fj * 16 + mrow;
            float bv = bias[col];
            #pragma unroll
            for (int r = 0; r < 4; ++r) {
                int row = m0 + wrow + fi * 16 + quad * 4 + r;
                float v = acc[fi][fj][r] + bv;
                if (RELU) {
                    outB[(size_t)row * N + col] = f2bf(fmaxf(v, 0.f));
                } else {
                    outF[(size_t)row * N + col] = v + resid[(size_t)row * N + col];
                }
            }
        }
}

// ---------------- LayerNorm: wave per row; optional bf16 copy ----------------
__global__ __launch_bounds__(256) void k_ln(const float* __restrict__ P,
    const float* __restrict__ g, const float* __restrict__ b,
    float* __restrict__ outF, bf16* __restrict__ outB) {
    int row = blockIdx.x * 4 + (threadIdx.x >> 6);
    int lane = threadIdx.x & 63;
    const float* p = P + (size_t)row * DMODEL + lane * 8;
    float4 a = *(const float4*)p;
    float4 c = *(const float4*)(p + 4);
    float s = a.x + a.y + a.z + a.w + c.x + c.y + c.z + c.w;
    #pragma unroll
    for (int off = 32; off > 0; off >>= 1) s += __shfl_xor(s, off, 64);
    float mean = s * (1.f / DMODEL);
    float d[8] = {a.x - mean, a.y - mean, a.z - mean, a.w - mean,
                  c.x - mean, c.y - mean, c.z - mean, c.w - mean};
    float vs = 0.f;
    #pragma unroll
    for (int j = 0; j < 8; ++j) vs += d[j] * d[j];
    #pragma unroll
    for (int off = 32; off > 0; off >>= 1) vs += __shfl_xor(vs, off, 64);
    float rstd = rsqrtf(vs * (1.f / DMODEL) + 1e-5f);
    float4 g0 = *(const float4*)(g + lane * 8);
    float4 g1 = *(const float4*)(g + lane * 8 + 4);
    float4 b0 = *(const float4*)(b + lane * 8);
    float4 b1 = *(const float4*)(b + lane * 8 + 4);
    float o[8] = {d[0] * rstd * g0.x + b0.x, d[1] * rstd * g0.y + b0.y,
                  d[2] * rstd * g0.z + b0.z, d[3] * rstd * g0.w + b0.w,
                  d[4] * rstd * g1.x + b1.x, d[5] * rstd * g1.y + b1.y,
                  d[6] * rstd * g1.z + b1.z, d[7] * rstd * g1.w + b1.w};
    float* of = outF + (size_t)row * DMODEL + lane * 8;
    *(float4*)of       = make_float4(o[0], o[1], o[2], o[3]);
    *(float4*)(of + 4) = make_float4(o[4], o[5], o[6], o[7]);
    if (outB) {
        bf16* ob = outB + (size_t)row * DMODEL + lane * 8;
        #pragma unroll
        for (int j = 0; j < 8; ++j) ob[j] = f2bf(o[j]);
    }
}

extern "C" void kernel_launch(void* const* d_in, const int* in_sizes, int n_in,
                              void* d_out, int out_size, void* d_ws, size_t ws_size,
                              hipStream_t stream) {
    const int*   src  = (const int*)d_in[0];
    const int*   mask = (const int*)d_in[1];
    const float* emb  = (const float*)d_in[2];
    const float* Wq   = (const float*)d_in[3];
    const float* bq   = (const float*)d_in[4];
    const float* Wk   = (const float*)d_in[5];
    const float* bk   = (const float*)d_in[6];
    const float* Wv   = (const float*)d_in[7];
    const float* bv   = (const float*)d_in[8];
    const float* Wo   = (const float*)d_in[9];
    const float* bo   = (const float*)d_in[10];
    const float* W1   = (const float*)d_in[11];
    const float* b1   = (const float*)d_in[12];
    const float* W2   = (const float*)d_in[13];
    const float* b2   = (const float*)d_in[14];
    const float* ln1g = (const float*)d_in[15];
    const float* ln1b = (const float*)d_in[16];
    const float* ln2g = (const float*)d_in[17];
    const float* ln2b = (const float*)d_in[18];

    const size_t NSD = (size_t)NS_TOK * DMODEL;
    float* h  = (float*)d_ws;            // 8.39 MB
    float* hb_f = h + NSD;               // 4.19 MB region
    bf16*  hb = (bf16*)hb_f;
    float* Mm = hb_f;                    // m/l scratch: alive only attn->comb,
    float* Ll = hb_f + 2 * NS_TOK * NHEAD;  // disjoint from hb's live range
    float* P  = hb_f + NSD / 2;          // 8.39 MB (attn partials alias this)
    bf16*  Po = (bf16*)P;                // [2][NS][D] bf16 = 8.39 MB exactly
    bf16*  Qb = (bf16*)(P + NSD);        // 4x 4.19 MB
    bf16*  Kb = Qb + NSD;
    bf16*  Vt = Kb + NSD;                // transposed V [(n,h,dim)][key]
    bf16*  Ab = Vt + NSD;
    bf16*  F1b = Qb;                     // aliases Qb..Ab, disjoint lifetime

    k_embed<<<NS_TOK, 256, 0, stream>>>(src, emb, h, hb);
    for (int l = 0; l < 6; ++l) {
        k_qkv<<<dim3(NS_TOK / 64, NHEAD), 256, 0, stream>>>(hb,
            Wq + (size_t)l * HDIM * HDIM, bq + l * HDIM,
            Wk + (size_t)l * HDIM * HDIM, bk + l * HDIM,
            Wv + (size_t)l * HDIM * HDIM, bv + l * HDIM,
            Qb, Kb, Vt);
        k_attn<<<dim3(SEQ / 64, NHEAD, NB * 2), 256, 0, stream>>>(
            Qb, Kb, Vt, mask, Po, Mm, Ll);
        k_comb<<<NS_TOK / 4, 256, 0, stream>>>(Po, Mm, Ll, Ab);
        k_gemm<64, false><<<dim3(NS_TOK / 64, DMODEL / 128), 256, 0, stream>>>(
            Ab, Wo + (size_t)l * DMODEL * DMODEL, bo + l * DMODEL,
            DMODEL, DMODEL, h, P, nullptr);
        k_ln<<<NS_TOK / 4, 256, 0, stream>>>(P, ln1g + l * DMODEL, ln1b + l * DMODEL, h, hb);
        k_gemm<128, true><<<dim3(NS_TOK / 128, FFDIM / 128), 256, 0, stream>>>(
            hb, W1 + (size_t)l * FFDIM * DMODEL, b1 + l * FFDIM,
            DMODEL, FFDIM, nullptr, nullptr, F1b);
        k_gemm<64, false><<<dim3(NS_TOK / 64, DMODEL / 128), 256, 0, stream>>>(
            F1b, W2 + (size_t)l * DMODEL * FFDIM, b2 + l * DMODEL,
            FFDIM, DMODEL, h, P, nullptr);
        float* lnout = (l == 5) ? (float*)d_out : h;
        bf16* lnoutB = (l == 5) ? nullptr : hb;
        k_ln<<<NS_TOK / 4, 256, 0, stream>>>(P, ln2g + l * DMODEL, ln2b + l * DMODEL, lnout, lnoutB);
    }
}

// Round 7
// 1150.769 us; speedup vs baseline: 8.1985x; 1.1579x over previous
//
#include <hip/hip_runtime.h>
#include <hip/hip_bf16.h>

// Encoder: L=6, D=512, H=8, HD=64, F=2048, V=32000, N=2, S=2048, NS=4096
// fp32 inputs/outputs. MFMA everywhere. Split-K(2) flash attention, exp2 softmax,
// row-sum folded into PV via ones-column. Weights pre-converted to bf16 when ws allows.
// ws: h(8.39) | hb(4.19, m/l alias) | P(8.39, partials alias) | Qb Kb Vt Ab (16.78) |
//     Wob W1b W2b (28.31) = 66.1 MB  (fp32-weight fallback if ws_size smaller)

#define NS_TOK 4096
#define DMODEL 512
#define NHEAD 8
#define HDIM 64
#define FFDIM 2048
#define SEQ 2048
#define NB 2

typedef __hip_bfloat16 bf16;
typedef __attribute__((ext_vector_type(8))) short short8;
typedef __attribute__((ext_vector_type(4))) float floatx4;

__device__ __forceinline__ float bf2f(bf16 x) { return __bfloat162float(x); }
__device__ __forceinline__ bf16 f2bf(float x) { return __float2bfloat16(x); }
__device__ __forceinline__ short bfbits(float x) {
    bf16 h = __float2bfloat16(x);
    return *reinterpret_cast<short*>(&h);
}
__device__ __forceinline__ float2 bf2x2(unsigned int u) {
    float2 r;
    r.x = __uint_as_float(u << 16);
    r.y = __uint_as_float(u & 0xffff0000u);
    return r;
}

// ---------------- weight fp32 -> bf16 conversion (once per launch) ----------------
__global__ __launch_bounds__(256) void k_conv(const float* __restrict__ src,
                                              bf16* __restrict__ dst, int count) {
    int i = (blockIdx.x * 256 + threadIdx.x) * 8;
    if (i >= count) return;
    float4 f0 = *(const float4*)(src + i);
    float4 f1 = *(const float4*)(src + i + 4);
    short8 sv;
    sv[0] = bfbits(f0.x); sv[1] = bfbits(f0.y);
    sv[2] = bfbits(f0.z); sv[3] = bfbits(f0.w);
    sv[4] = bfbits(f1.x); sv[5] = bfbits(f1.y);
    sv[6] = bfbits(f1.z); sv[7] = bfbits(f1.w);
    *(short8*)(dst + i) = sv;
}

// ---------------- embed: h fp32 + hb bf16 ----------------
__global__ __launch_bounds__(256) void k_embed(const int* __restrict__ src,
                                               const float* __restrict__ emb,
                                               float* __restrict__ h,
                                               bf16* __restrict__ hb) {
    int row = blockIdx.x;
    int t = threadIdx.x;
    int tok = src[row];
    const float* e = emb + (size_t)tok * DMODEL;
    float v0 = e[t] * 22.62741699796952f;
    float v1 = e[t + 256] * 22.62741699796952f;
    h[(size_t)row * DMODEL + t] = v0;
    h[(size_t)row * DMODEL + t + 256] = v1;
    hb[(size_t)row * DMODEL + t] = f2bf(v0);
    hb[(size_t)row * DMODEL + t + 256] = f2bf(v1);
}

// ---------------- QKV via MFMA: block = (64-token tile, head) ----------------
__global__ __launch_bounds__(256) void k_qkv(const bf16* __restrict__ hb,
    const float* __restrict__ Wq, const float* __restrict__ bq,
    const float* __restrict__ Wk, const float* __restrict__ bk,
    const float* __restrict__ Wv, const float* __restrict__ bv,
    bf16* __restrict__ Qo, bf16* __restrict__ Ko, bf16* __restrict__ Vt) {
    __shared__ short Xs[64 * 72];
    __shared__ short Ws3[3][64 * 72];
    int t = threadIdx.x, lane = t & 63, w = t >> 6;
    int l15 = lane & 15, quad = lane >> 4;
    int tok0 = blockIdx.x * 64, hh = blockIdx.y;
    int n = tok0 >> 11, s0loc = tok0 & 2047;
    const float* Ws[3] = {Wq, Wk, Wv};
    const float* Bs[3] = {bq, bk, bv};

    #pragma unroll
    for (int i = 0; i < 2; ++i) {
        int idx = t + i * 256;
        int row = idx >> 3, g = idx & 7;
        *(uint4*)&Xs[row * 72 + g * 8] =
            *(const uint4*)(hb + (size_t)(tok0 + row) * DMODEL + hh * HDIM + g * 8);
    }
    #pragma unroll
    for (int tn = 0; tn < 3; ++tn)
        #pragma unroll
        for (int i = 0; i < 2; ++i) {
            int idx = t + i * 256;
            int row = idx >> 3, g = idx & 7;
            const float* srcp = Ws[tn] + row * HDIM + g * 8;
            float4 f0 = *(const float4*)srcp;
            float4 f1 = *(const float4*)(srcp + 4);
            short8 sv;
            sv[0] = bfbits(f0.x); sv[1] = bfbits(f0.y);
            sv[2] = bfbits(f0.z); sv[3] = bfbits(f0.w);
            sv[4] = bfbits(f1.x); sv[5] = bfbits(f1.y);
            sv[6] = bfbits(f1.z); sv[7] = bfbits(f1.w);
            *(short8*)&Ws3[tn][row * 72 + g * 8] = sv;
        }
    __syncthreads();
    short8 aq[2];
    aq[0] = *(short8*)&Xs[(w * 16 + l15) * 72 + quad * 8];
    aq[1] = *(short8*)&Xs[(w * 16 + l15) * 72 + 32 + quad * 8];

    #pragma unroll
    for (int tn = 0; tn < 3; ++tn) {
        floatx4 acc[4];
        #pragma unroll
        for (int fj = 0; fj < 4; ++fj)
            #pragma unroll
            for (int r = 0; r < 4; ++r) acc[fj][r] = 0.f;
        #pragma unroll
        for (int ks = 0; ks < 2; ++ks)
            #pragma unroll
            for (int fj = 0; fj < 4; ++fj) {
                short8 bfrag = *(short8*)&Ws3[tn][(fj * 16 + l15) * 72 + ks * 32 + quad * 8];
                acc[fj] = __builtin_amdgcn_mfma_f32_16x16x32_bf16(aq[ks], bfrag, acc[fj], 0, 0, 0);
            }
        #pragma unroll
        for (int fj = 0; fj < 4; ++fj) {
            int col = fj * 16 + l15;
            float bias = Bs[tn][col];
            if (tn < 2) {
                bf16* O = (tn == 0) ? Qo : Ko;
                #pragma unroll
                for (int r = 0; r < 4; ++r) {
                    int tok = tok0 + w * 16 + quad * 4 + r;
                    O[(size_t)tok * DMODEL + hh * HDIM + col] = f2bf(acc[fj][r] + bias);
                }
            } else {
                short4 pk;
                pk.x = bfbits(acc[fj][0] + bias); pk.y = bfbits(acc[fj][1] + bias);
                pk.z = bfbits(acc[fj][2] + bias); pk.w = bfbits(acc[fj][3] + bias);
                int sl = s0loc + w * 16 + quad * 4;
                *(short4*)(Vt + ((size_t)((n * NHEAD + hh) * HDIM + col)) * SEQ + sl) = pk;
            }
        }
    }
}

// ---------------- MFMA flash attention, split-K(2), exp2 softmax ----------------
// l (row sum) folded into PV via a constant ones-row at dim 64 of the V tile:
// accO[4] carries l through the same alpha-rescale recurrence as O.
__global__ __launch_bounds__(256) void k_attn(const bf16* __restrict__ Qb,
                                              const bf16* __restrict__ Kb,
                                              const bf16* __restrict__ Vt,
                                              const int* __restrict__ mask,
                                              bf16* __restrict__ Po,
                                              float* __restrict__ Mm,
                                              float* __restrict__ Ll) {
    __shared__ short Qs[64 * 72];
    __shared__ short Ks[64 * 72];
    __shared__ short Vs[80 * 72];     // rows 0-63: V^T tile; row 64: ones; 65-79: zero
    __shared__ short Ps[4][16 * 72];
    int t = threadIdx.x, lane = t & 63, w = t >> 6;
    int l15 = lane & 15, quad = lane >> 4;
    int q0 = blockIdx.x * 64, hh = blockIdx.y;
    int n = blockIdx.z >> 1, sp = blockIdx.z & 1;
    const float SCALE2 = 0.044194173824159216f * 1.44269504088896341f;
    size_t tokbase = (size_t)n * SEQ;
    size_t vbase = ((size_t)(n * NHEAD + hh) * HDIM) * SEQ;

    #pragma unroll
    for (int i = 0; i < 2; ++i) {
        int idx = t + 256 * i;
        int row = idx >> 3, q = idx & 7;
        *(uint4*)&Qs[row * 72 + q * 8] =
            *(const uint4*)(Qb + (tokbase + q0 + row) * DMODEL + hh * HDIM + q * 8);
    }
    for (int j = t; j < 16 * 72; j += 256) Vs[64 * 72 + j] = 0;   // zero rows 64-79
    if (t < 64) Vs[64 * 72 + t] = (short)0x3F80;                  // ones row (dim 64)
    __syncthreads();
    short8 aq[2];
    aq[0] = *(short8*)&Qs[(w * 16 + l15) * 72 + quad * 8];
    aq[1] = *(short8*)&Qs[(w * 16 + l15) * 72 + 32 + quad * 8];

    floatx4 accO[5];
    float mold[4];
    #pragma unroll
    for (int fn = 0; fn < 5; ++fn)
        #pragma unroll
        for (int r = 0; r < 4; ++r) accO[fn][r] = 0.f;
    #pragma unroll
    for (int r = 0; r < 4; ++r) mold[r] = -1.0e38f;

    int kbeg = sp * (SEQ / 2), kend = kbeg + SEQ / 2;
    for (int k0 = kbeg; k0 < kend; k0 += 64) {
        __syncthreads();
        #pragma unroll
        for (int i = 0; i < 2; ++i) {
            int idx = t + 256 * i;
            int row = idx >> 3, q = idx & 7;
            *(uint4*)&Ks[row * 72 + q * 8] =
                *(const uint4*)(Kb + (tokbase + k0 + row) * DMODEL + hh * HDIM + q * 8);
            *(uint4*)&Vs[row * 72 + q * 8] =
                *(const uint4*)(Vt + vbase + (size_t)row * SEQ + k0 + q * 8);
        }
        __syncthreads();
        floatx4 accS[4];
        #pragma unroll
        for (int fj = 0; fj < 4; ++fj)
            #pragma unroll
            for (int r = 0; r < 4; ++r) accS[fj][r] = 0.f;
        #pragma unroll
        for (int ks = 0; ks < 2; ++ks)
            #pragma unroll
            for (int fj = 0; fj < 4; ++fj) {
                short8 bk = *(short8*)&Ks[(fj * 16 + l15) * 72 + ks * 32 + quad * 8];
                accS[fj] = __builtin_amdgcn_mfma_f32_16x16x32_bf16(aq[ks], bk, accS[fj], 0, 0, 0);
            }
        #pragma unroll
        for (int fj = 0; fj < 4; ++fj) {
            int mk = mask[n * SEQ + k0 + fj * 16 + l15];
            #pragma unroll
            for (int r = 0; r < 4; ++r)
                accS[fj][r] = mk ? accS[fj][r] * SCALE2 : -1.0e9f;
        }
        float al[4];
        #pragma unroll
        for (int r = 0; r < 4; ++r) {
            float mx = fmaxf(fmaxf(accS[0][r], accS[1][r]), fmaxf(accS[2][r], accS[3][r]));
            mx = fmaxf(mx, __shfl_xor(mx, 1, 64));
            mx = fmaxf(mx, __shfl_xor(mx, 2, 64));
            mx = fmaxf(mx, __shfl_xor(mx, 4, 64));
            mx = fmaxf(mx, __shfl_xor(mx, 8, 64));
            float mn = fmaxf(mold[r], mx);
            al[r] = exp2f(mold[r] - mn);
            mold[r] = mn;
            #pragma unroll
            for (int fj = 0; fj < 4; ++fj) {
                float p = exp2f(accS[fj][r] - mn);
                Ps[w][(quad * 4 + r) * 72 + fj * 16 + l15] = bfbits(p);
            }
        }
        #pragma unroll
        for (int fn = 0; fn < 5; ++fn)
            #pragma unroll
            for (int r = 0; r < 4; ++r) accO[fn][r] *= al[r];
        #pragma unroll
        for (int ks = 0; ks < 2; ++ks) {
            short8 ap = *(short8*)&Ps[w][l15 * 72 + ks * 32 + quad * 8];
            #pragma unroll
            for (int fn = 0; fn < 5; ++fn) {
                short8 bv = *(short8*)&Vs[(fn * 16 + l15) * 72 + ks * 32 + quad * 8];
                accO[fn] = __builtin_amdgcn_mfma_f32_16x16x32_bf16(ap, bv, accO[fn], 0, 0, 0);
            }
        }
    }
    // epilogue: unnormalized O + (m, l); l lives in col 0 of accO[4] -> broadcast
    #pragma unroll
    for (int r = 0; r < 4; ++r) {
        float ls = __shfl(accO[4][r], lane & 48);   // col 0 of this row group
        int row = q0 + w * 16 + quad * 4 + r;
        size_t gtok = tokbase + row;
        bf16* dst = Po + ((size_t)sp * NS_TOK + gtok) * DMODEL + hh * HDIM;
        #pragma unroll
        for (int fn = 0; fn < 4; ++fn)
            dst[fn * 16 + l15] = f2bf(accO[fn][r]);
        if (l15 == 0) {
            Mm[((size_t)sp * NS_TOK + gtok) * NHEAD + hh] = mold[r];
            Ll[((size_t)sp * NS_TOK + gtok) * NHEAD + hh] = ls;
        }
    }
}

// ---------------- combine the two K-splits ----------------
__global__ __launch_bounds__(256) void k_comb(const bf16* __restrict__ Po,
    const float* __restrict__ Mm, const float* __restrict__ Ll,
    bf16* __restrict__ Ab) {
    int tok = blockIdx.x * 4 + (threadIdx.x >> 6);
    int lane = threadIdx.x & 63;
    int hh = lane >> 3;
    float m1 = Mm[(size_t)tok * NHEAD + hh];
    float m2 = Mm[((size_t)NS_TOK + tok) * NHEAD + hh];
    float l1 = Ll[(size_t)tok * NHEAD + hh];
    float l2 = Ll[((size_t)NS_TOK + tok) * NHEAD + hh];
    float m = fmaxf(m1, m2);
    float w1 = exp2f(m1 - m), w2 = exp2f(m2 - m);
    float inv = 1.f / (l1 * w1 + l2 * w2);
    uint4 u1 = *(const uint4*)(Po + (size_t)tok * DMODEL + lane * 8);
    uint4 u2 = *(const uint4*)(Po + ((size_t)NS_TOK + tok) * DMODEL + lane * 8);
    bf16* dst = Ab + (size_t)tok * DMODEL + lane * 8;
    const unsigned int* p1 = (const unsigned int*)&u1;
    const unsigned int* p2 = (const unsigned int*)&u2;
    #pragma unroll
    for (int j = 0; j < 4; ++j) {
        float2 a = bf2x2(p1[j]), b = bf2x2(p2[j]);
        dst[j * 2]     = f2bf((a.x * w1 + b.x * w2) * inv);
        dst[j * 2 + 1] = f2bf((a.y * w1 + b.y * w2) * inv);
    }
}

// ---------------- MFMA GEMM: C[M,N] = A[M,K](bf16) @ W[N,K]^T ----------------
// WBF: weights already bf16 (pre-converted); else fp32 with on-the-fly convert.
template<int MT, bool RELU, bool WBF>
__global__ __launch_bounds__(256) void k_gemm(const bf16* __restrict__ A,
    const void* __restrict__ Wp, const float* __restrict__ bias, int K, int N,
    const float* __restrict__ resid, float* __restrict__ outF, bf16* __restrict__ outB) {
    constexpr int FI = 4;
    constexpr int FJ = (MT == 128) ? 4 : 2;
    __shared__ short As[MT * 40];
    __shared__ short Bs[128 * 40];
    int t = threadIdx.x, lane = t & 63, w = t >> 6;
    int m0 = blockIdx.x * MT, n0 = blockIdx.y * 128;
    int wrow = (MT == 128) ? (w >> 1) * 64 : 0;
    int wcol = (MT == 128) ? (w & 1) * 64 : w * 32;
    int quad = lane >> 4, mrow = lane & 15;
    floatx4 acc[FI][FJ];
    #pragma unroll
    for (int fi = 0; fi < FI; ++fi)
        #pragma unroll
        for (int fj = 0; fj < FJ; ++fj)
            #pragma unroll
            for (int r = 0; r < 4; ++r) acc[fi][fj][r] = 0.f;

    for (int k0 = 0; k0 < K; k0 += 32) {
        __syncthreads();
        #pragma unroll
        for (int i = 0; i < MT / 64; ++i) {
            int idx = t + i * 256;
            int row = idx >> 2, q = idx & 3;
            uint4 u = *(const uint4*)(A + (size_t)(m0 + row) * K + k0 + q * 8);
            *(uint4*)&As[row * 40 + q * 8] = u;
        }
        #pragma unroll
        for (int i = 0; i < 2; ++i) {
            int idx = t + i * 256;
            int row = idx >> 2, q = idx & 3;
            if (WBF) {
                const bf16* Wb = (const bf16*)Wp;
                uint4 u = *(const uint4*)(Wb + (size_t)(n0 + row) * K + k0 + q * 8);
                *(uint4*)&Bs[row * 40 + q * 8] = u;
            } else {
                const float* Wf = (const float*)Wp;
                const float* src = Wf + (size_t)(n0 + row) * K + k0 + q * 8;
                float4 f0 = *(const float4*)src;
                float4 f1 = *(const float4*)(src + 4);
                short8 sv;
                sv[0] = bfbits(f0.x); sv[1] = bfbits(f0.y);
                sv[2] = bfbits(f0.z); sv[3] = bfbits(f0.w);
                sv[4] = bfbits(f1.x); sv[5] = bfbits(f1.y);
                sv[6] = bfbits(f1.z); sv[7] = bfbits(f1.w);
                *(short8*)&Bs[row * 40 + q * 8] = sv;
            }
        }
        __syncthreads();
        short8 af[FI], bfr[FJ];
        #pragma unroll
        for (int fi = 0; fi < FI; ++fi)
            af[fi] = *(short8*)&As[(wrow + fi * 16 + mrow) * 40 + quad * 8];
        #pragma unroll
        for (int fj = 0; fj < FJ; ++fj)
            bfr[fj] = *(short8*)&Bs[(wcol + fj * 16 + mrow) * 40 + quad * 8];
        #pragma unroll
        for (int fi = 0; fi < FI; ++fi)
            #pragma unroll
            for (int fj = 0; fj < FJ; ++fj)
                acc[fi][fj] = __builtin_amdgcn_mfma_f32_16x16x32_bf16(
                    af[fi], bfr[fj], acc[fi][fj], 0, 0, 0);
    }
    #pragma unroll
    for (int fi = 0; fi < FI; ++fi)
        #pragma unroll
        for (int fj = 0; fj < FJ; ++fj) {
            int col = n0 + wcol + fj * 16 + mrow;
            float bv = bias[col];
            #pragma unroll
            for (int r = 0; r < 4; ++r) {
                int row = m0 + wrow + fi * 16 + quad * 4 + r;
                float v = acc[fi][fj][r] + bv;
                if (RELU) {
                    outB[(size_t)row * N + col] = f2bf(fmaxf(v, 0.f));
                } else {
                    outF[(size_t)row * N + col] = v + resid[(size_t)row * N + col];
                }
            }
        }
}

// ---------------- LayerNorm: wave per row; optional bf16 copy ----------------
__global__ __launch_bounds__(256) void k_ln(const float* __restrict__ P,
    const float* __restrict__ g, const float* __restrict__ b,
    float* __restrict__ outF, bf16* __restrict__ outB) {
    int row = blockIdx.x * 4 + (threadIdx.x >> 6);
    int lane = threadIdx.x & 63;
    const float* p = P + (size_t)row * DMODEL + lane * 8;
    float4 a = *(const float4*)p;
    float4 c = *(const float4*)(p + 4);
    float s = a.x + a.y + a.z + a.w + c.x + c.y + c.z + c.w;
    #pragma unroll
    for (int off = 32; off > 0; off >>= 1) s += __shfl_xor(s, off, 64);
    float mean = s * (1.f / DMODEL);
    float d[8] = {a.x - mean, a.y - mean, a.z - mean, a.w - mean,
                  c.x - mean, c.y - mean, c.z - mean, c.w - mean};
    float vs = 0.f;
    #pragma unroll
    for (int j = 0; j < 8; ++j) vs += d[j] * d[j];
    #pragma unroll
    for (int off = 32; off > 0; off >>= 1) vs += __shfl_xor(vs, off, 64);
    float rstd = rsqrtf(vs * (1.f / DMODEL) + 1e-5f);
    float4 g0 = *(const float4*)(g + lane * 8);
    float4 g1 = *(const float4*)(g + lane * 8 + 4);
    float4 b0 = *(const float4*)(b + lane * 8);
    float4 b1 = *(const float4*)(b + lane * 8 + 4);
    float o[8] = {d[0] * rstd * g0.x + b0.x, d[1] * rstd * g0.y + b0.y,
                  d[2] * rstd * g0.z + b0.z, d[3] * rstd * g0.w + b0.w,
                  d[4] * rstd * g1.x + b1.x, d[5] * rstd * g1.y + b1.y,
                  d[6] * rstd * g1.z + b1.z, d[7] * rstd * g1.w + b1.w};
    float* of = outF + (size_t)row * DMODEL + lane * 8;
    *(float4*)of       = make_float4(o[0], o[1], o[2], o[3]);
    *(float4*)(of + 4) = make_float4(o[4], o[5], o[6], o[7]);
    if (outB) {
        bf16* ob = outB + (size_t)row * DMODEL + lane * 8;
        #pragma unroll
        for (int j = 0; j < 8; ++j) ob[j] = f2bf(o[j]);
    }
}

extern "C" void kernel_launch(void* const* d_in, const int* in_sizes, int n_in,
                              void* d_out, int out_size, void* d_ws, size_t ws_size,
                              hipStream_t stream) {
    const int*   src  = (const int*)d_in[0];
    const int*   mask = (const int*)d_in[1];
    const float* emb  = (const float*)d_in[2];
    const float* Wq   = (const float*)d_in[3];
    const float* bq   = (const float*)d_in[4];
    const float* Wk   = (const float*)d_in[5];
    const float* bk   = (const float*)d_in[6];
    const float* Wv   = (const float*)d_in[7];
    const float* bv   = (const float*)d_in[8];
    const float* Wo   = (const float*)d_in[9];
    const float* bo   = (const float*)d_in[10];
    const float* W1   = (const float*)d_in[11];
    const float* b1   = (const float*)d_in[12];
    const float* W2   = (const float*)d_in[13];
    const float* b2   = (const float*)d_in[14];
    const float* ln1g = (const float*)d_in[15];
    const float* ln1b = (const float*)d_in[16];
    const float* ln2g = (const float*)d_in[17];
    const float* ln2b = (const float*)d_in[18];

    const size_t NSD = (size_t)NS_TOK * DMODEL;
    float* h  = (float*)d_ws;            // 8.39 MB
    float* hb_f = h + NSD;               // 4.19 MB region
    bf16*  hb = (bf16*)hb_f;
    float* Mm = hb_f;                    // m/l scratch aliases hb (disjoint live ranges)
    float* Ll = hb_f + 2 * NS_TOK * NHEAD;
    float* P  = hb_f + NSD / 2;          // 8.39 MB (attn partials alias)
    bf16*  Po = (bf16*)P;
    bf16*  Qb = (bf16*)(P + NSD);        // 4x 4.19 MB
    bf16*  Kb = Qb + NSD;
    bf16*  Vt = Kb + NSD;
    bf16*  Ab = Vt + NSD;
    bf16*  F1b = Qb;                     // aliases Qb..Ab, disjoint lifetime
    // pre-converted weights (after Ab): Wo 1.57M, W1 6.29M, W2 6.29M elems
    bf16*  Wob = Ab + NSD;
    bf16*  W1b = Wob + (size_t)6 * DMODEL * DMODEL;
    bf16*  W2b = W1b + (size_t)6 * FFDIM * DMODEL;
    const size_t NEED = (size_t)(Ab + NSD - (bf16*)d_ws) * 2 +
                        ((size_t)6 * DMODEL * DMODEL + 2 * (size_t)6 * FFDIM * DMODEL) * 2;
    bool useWb = ws_size >= NEED;

    if (useWb) {
        k_conv<<<(6 * DMODEL * DMODEL) / 2048, 256, 0, stream>>>(Wo, Wob, 6 * DMODEL * DMODEL);
        k_conv<<<(6 * FFDIM * DMODEL) / 2048, 256, 0, stream>>>(W1, W1b, 6 * FFDIM * DMODEL);
        k_conv<<<(6 * FFDIM * DMODEL) / 2048, 256, 0, stream>>>(W2, W2b, 6 * FFDIM * DMODEL);
    }
    k_embed<<<NS_TOK, 256, 0, stream>>>(src, emb, h, hb);
    for (int l = 0; l < 6; ++l) {
        k_qkv<<<dim3(NS_TOK / 64, NHEAD), 256, 0, stream>>>(hb,
            Wq + (size_t)l * HDIM * HDIM, bq + l * HDIM,
            Wk + (size_t)l * HDIM * HDIM, bk + l * HDIM,
            Wv + (size_t)l * HDIM * HDIM, bv + l * HDIM,
            Qb, Kb, Vt);
        k_attn<<<dim3(SEQ / 64, NHEAD, NB * 2), 256, 0, stream>>>(
            Qb, Kb, Vt, mask, Po, Mm, Ll);
        k_comb<<<NS_TOK / 4, 256, 0, stream>>>(Po, Mm, Ll, Ab);
        if (useWb) {
            k_gemm<64, false, true><<<dim3(NS_TOK / 64, DMODEL / 128), 256, 0, stream>>>(
                Ab, Wob + (size_t)l * DMODEL * DMODEL, bo + l * DMODEL,
                DMODEL, DMODEL, h, P, nullptr);
        } else {
            k_gemm<64, false, false><<<dim3(NS_TOK / 64, DMODEL / 128), 256, 0, stream>>>(
                Ab, Wo + (size_t)l * DMODEL * DMODEL, bo + l * DMODEL,
                DMODEL, DMODEL, h, P, nullptr);
        }
        k_ln<<<NS_TOK / 4, 256, 0, stream>>>(P, ln1g + l * DMODEL, ln1b + l * DMODEL, h, hb);
        if (useWb) {
            k_gemm<128, true, true><<<dim3(NS_TOK / 128, FFDIM / 128), 256, 0, stream>>>(
                hb, W1b + (size_t)l * FFDIM * DMODEL, b1 + l * FFDIM,
                DMODEL, FFDIM, nullptr, nullptr, F1b);
            k_gemm<64, false, true><<<dim3(NS_TOK / 64, DMODEL / 128), 256, 0, stream>>>(
                F1b, W2b + (size_t)l * DMODEL * FFDIM, b2 + l * DMODEL,
                FFDIM, DMODEL, h, P, nullptr);
        } else {
            k_gemm<128, true, false><<<dim3(NS_TOK / 128, FFDIM / 128), 256, 0, stream>>>(
                hb, W1 + (size_t)l * FFDIM * DMODEL, b1 + l * FFDIM,
                DMODEL, FFDIM, nullptr, nullptr, F1b);
            k_gemm<64, false, false><<<dim3(NS_TOK / 64, DMODEL / 128), 256, 0, stream>>>(
                F1b, W2 + (size_t)l * DMODEL * FFDIM, b2 + l * DMODEL,
                FFDIM, DMODEL, h, P, nullptr);
        }
        float* lnout = (l == 5) ? (float*)d_out : h;
        bf16* lnoutB = (l == 5) ? nullptr : hb;
        k_ln<<<NS_TOK / 4, 256, 0, stream>>>(P, ln2g + l * DMODEL, ln2b + l * DMODEL, lnout, lnoutB);
    }
}

// Round 8
// 1010.298 us; speedup vs baseline: 9.3385x; 1.1390x over previous
//
#include <hip/hip_runtime.h>
#include <hip/hip_bf16.h>

// Encoder: L=6, D=512, H=8, HD=64, F=2048, V=32000, N=2, S=2048, NS=4096
// fp32 in/out. MFMA everywhere. Split-K(4) flash attention (exp2 softmax, l via
// ones-column, scale folded into Q). GEMMs: global_load_lds staging; N=512 GEMMs
// split-K(2) with combine+bias+resid+LN fused into k_lncomb.
// ws tiers: 74.4 MB full | 66 MB no-splitK-gemm | 37.7 MB fp32-weight fallback.

#define NS_TOK 4096
#define DMODEL 512
#define NHEAD 8
#define HDIM 64
#define FFDIM 2048
#define SEQ 2048
#define NB 2

typedef __hip_bfloat16 bf16;
typedef __attribute__((ext_vector_type(8))) short short8;
typedef __attribute__((ext_vector_type(4))) float floatx4;

__device__ __forceinline__ float bf2f(bf16 x) { return __bfloat162float(x); }
__device__ __forceinline__ bf16 f2bf(float x) { return __float2bfloat16(x); }
__device__ __forceinline__ short bfbits(float x) {
    bf16 h = __float2bfloat16(x);
    return *reinterpret_cast<short*>(&h);
}
__device__ __forceinline__ float2 bf2x2(unsigned int u) {
    float2 r;
    r.x = __uint_as_float(u << 16);
    r.y = __uint_as_float(u & 0xffff0000u);
    return r;
}
// async global->LDS, 16B/lane; LDS dest is wave-uniform base + lane*16
__device__ __forceinline__ void gl2lds16(const void* g, void* l) {
    __builtin_amdgcn_global_load_lds(
        (const __attribute__((address_space(1))) void*)g,
        (__attribute__((address_space(3))) void*)l, 16, 0, 0);
}

// ---------------- weight fp32 -> bf16 conversion ----------------
__global__ __launch_bounds__(256) void k_conv(const float* __restrict__ src,
                                              bf16* __restrict__ dst, int count) {
    int i = (blockIdx.x * 256 + threadIdx.x) * 8;
    if (i >= count) return;
    float4 f0 = *(const float4*)(src + i);
    float4 f1 = *(const float4*)(src + i + 4);
    short8 sv;
    sv[0] = bfbits(f0.x); sv[1] = bfbits(f0.y);
    sv[2] = bfbits(f0.z); sv[3] = bfbits(f0.w);
    sv[4] = bfbits(f1.x); sv[5] = bfbits(f1.y);
    sv[6] = bfbits(f1.z); sv[7] = bfbits(f1.w);
    *(short8*)(dst + i) = sv;
}

// ---------------- embed ----------------
__global__ __launch_bounds__(256) void k_embed(const int* __restrict__ src,
                                               const float* __restrict__ emb,
                                               float* __restrict__ h,
                                               bf16* __restrict__ hb) {
    int row = blockIdx.x;
    int t = threadIdx.x;
    int tok = src[row];
    const float* e = emb + (size_t)tok * DMODEL;
    float v0 = e[t] * 22.62741699796952f;
    float v1 = e[t + 256] * 22.62741699796952f;
    h[(size_t)row * DMODEL + t] = v0;
    h[(size_t)row * DMODEL + t + 256] = v1;
    hb[(size_t)row * DMODEL + t] = f2bf(v0);
    hb[(size_t)row * DMODEL + t + 256] = f2bf(v1);
}

// ---------------- QKV via MFMA; Q pre-scaled by 1/sqrt(512)*log2e ----------------
__global__ __launch_bounds__(256) void k_qkv(const bf16* __restrict__ hb,
    const float* __restrict__ Wq, const float* __restrict__ bq,
    const float* __restrict__ Wk, const float* __restrict__ bk,
    const float* __restrict__ Wv, const float* __restrict__ bv,
    bf16* __restrict__ Qo, bf16* __restrict__ Ko, bf16* __restrict__ Vt) {
    __shared__ __align__(16) short Xs[64 * 72];
    __shared__ __align__(16) short Ws3[3][64 * 72];
    int t = threadIdx.x, lane = t & 63, w = t >> 6;
    int l15 = lane & 15, quad = lane >> 4;
    int tok0 = blockIdx.x * 64, hh = blockIdx.y;
    int n = tok0 >> 11, s0loc = tok0 & 2047;
    const float QSC = 0.044194173824159216f * 1.44269504088896341f;
    const float* Ws[3] = {Wq, Wk, Wv};
    const float* Bs[3] = {bq, bk, bv};

    #pragma unroll
    for (int i = 0; i < 2; ++i) {
        int idx = t + i * 256;
        int row = idx >> 3, g = idx & 7;
        *(uint4*)&Xs[row * 72 + g * 8] =
            *(const uint4*)(hb + (size_t)(tok0 + row) * DMODEL + hh * HDIM + g * 8);
    }
    #pragma unroll
    for (int tn = 0; tn < 3; ++tn)
        #pragma unroll
        for (int i = 0; i < 2; ++i) {
            int idx = t + i * 256;
            int row = idx >> 3, g = idx & 7;
            const float* srcp = Ws[tn] + row * HDIM + g * 8;
            float4 f0 = *(const float4*)srcp;
            float4 f1 = *(const float4*)(srcp + 4);
            short8 sv;
            sv[0] = bfbits(f0.x); sv[1] = bfbits(f0.y);
            sv[2] = bfbits(f0.z); sv[3] = bfbits(f0.w);
            sv[4] = bfbits(f1.x); sv[5] = bfbits(f1.y);
            sv[6] = bfbits(f1.z); sv[7] = bfbits(f1.w);
            *(short8*)&Ws3[tn][row * 72 + g * 8] = sv;
        }
    __syncthreads();
    short8 aq[2];
    aq[0] = *(short8*)&Xs[(w * 16 + l15) * 72 + quad * 8];
    aq[1] = *(short8*)&Xs[(w * 16 + l15) * 72 + 32 + quad * 8];

    #pragma unroll
    for (int tn = 0; tn < 3; ++tn) {
        floatx4 acc[4];
        #pragma unroll
        for (int fj = 0; fj < 4; ++fj)
            #pragma unroll
            for (int r = 0; r < 4; ++r) acc[fj][r] = 0.f;
        #pragma unroll
        for (int ks = 0; ks < 2; ++ks)
            #pragma unroll
            for (int fj = 0; fj < 4; ++fj) {
                short8 bfrag = *(short8*)&Ws3[tn][(fj * 16 + l15) * 72 + ks * 32 + quad * 8];
                acc[fj] = __builtin_amdgcn_mfma_f32_16x16x32_bf16(aq[ks], bfrag, acc[fj], 0, 0, 0);
            }
        #pragma unroll
        for (int fj = 0; fj < 4; ++fj) {
            int col = fj * 16 + l15;
            float bias = Bs[tn][col];
            if (tn < 2) {
                bf16* O = (tn == 0) ? Qo : Ko;
                float sc = (tn == 0) ? QSC : 1.f;
                #pragma unroll
                for (int r = 0; r < 4; ++r) {
                    int tok = tok0 + w * 16 + quad * 4 + r;
                    O[(size_t)tok * DMODEL + hh * HDIM + col] = f2bf((acc[fj][r] + bias) * sc);
                }
            } else {
                short4 pk;
                pk.x = bfbits(acc[fj][0] + bias); pk.y = bfbits(acc[fj][1] + bias);
                pk.z = bfbits(acc[fj][2] + bias); pk.w = bfbits(acc[fj][3] + bias);
                int sl = s0loc + w * 16 + quad * 4;
                *(short4*)(Vt + ((size_t)((n * NHEAD + hh) * HDIM + col)) * SEQ + sl) = pk;
            }
        }
    }
}

// ---------------- MFMA flash attention, split-K (2 or 4), exp2 softmax ----------
// P-slab aliases the dead Q-staging LDS (wave w's P slab == wave w's own Q rows).
__global__ __launch_bounds__(256) void k_attn(const bf16* __restrict__ Qb,
                                              const bf16* __restrict__ Kb,
                                              const bf16* __restrict__ Vt,
                                              const int* __restrict__ mask,
                                              bf16* __restrict__ PoA,
                                              bf16* __restrict__ PoB,
                                              float* __restrict__ Mm,
                                              float* __restrict__ Ll,
                                              int ns_l2) {
    __shared__ __align__(16) short QPs[64 * 72];   // Q staging, then P slabs
    __shared__ __align__(16) short Ks[64 * 72];
    __shared__ __align__(16) short Vs[80 * 72];    // 0-63 V^T; 64 ones; 65-79 zero
    int t = threadIdx.x, lane = t & 63, w = t >> 6;
    int l15 = lane & 15, quad = lane >> 4;
    int q0 = blockIdx.x * 64, hh = blockIdx.y;
    int z = blockIdx.z;
    int n = z >> ns_l2, sp = z & ((1 << ns_l2) - 1);
    size_t tokbase = (size_t)n * SEQ;
    size_t vbase = ((size_t)(n * NHEAD + hh) * HDIM) * SEQ;

    #pragma unroll
    for (int i = 0; i < 2; ++i) {
        int idx = t + 256 * i;
        int row = idx >> 3, q = idx & 7;
        *(uint4*)&QPs[row * 72 + q * 8] =
            *(const uint4*)(Qb + (tokbase + q0 + row) * DMODEL + hh * HDIM + q * 8);
    }
    for (int j = t; j < 16 * 72; j += 256) Vs[64 * 72 + j] = 0;
    if (t < 64) Vs[64 * 72 + t] = (short)0x3F80;   // bf16 1.0 ones-row (dim 64)
    __syncthreads();
    short8 aq[2];
    aq[0] = *(short8*)&QPs[(w * 16 + l15) * 72 + quad * 8];
    aq[1] = *(short8*)&QPs[(w * 16 + l15) * 72 + 32 + quad * 8];

    floatx4 accO[5];
    float mold[4];
    #pragma unroll
    for (int fn = 0; fn < 5; ++fn)
        #pragma unroll
        for (int r = 0; r < 4; ++r) accO[fn][r] = 0.f;
    #pragma unroll
    for (int r = 0; r < 4; ++r) mold[r] = -1.0e38f;

    int kquota = SEQ >> ns_l2;
    int kbeg = sp * kquota, kend = kbeg + kquota;
    for (int k0 = kbeg; k0 < kend; k0 += 64) {
        __syncthreads();
        #pragma unroll
        for (int i = 0; i < 2; ++i) {
            int idx = t + 256 * i;
            int row = idx >> 3, q = idx & 7;
            *(uint4*)&Ks[row * 72 + q * 8] =
                *(const uint4*)(Kb + (tokbase + k0 + row) * DMODEL + hh * HDIM + q * 8);
            *(uint4*)&Vs[row * 72 + q * 8] =
                *(const uint4*)(Vt + vbase + (size_t)row * SEQ + k0 + q * 8);
        }
        __syncthreads();
        floatx4 accS[4];
        #pragma unroll
        for (int fj = 0; fj < 4; ++fj)
            #pragma unroll
            for (int r = 0; r < 4; ++r) accS[fj][r] = 0.f;
        #pragma unroll
        for (int ks = 0; ks < 2; ++ks)
            #pragma unroll
            for (int fj = 0; fj < 4; ++fj) {
                short8 bk = *(short8*)&Ks[(fj * 16 + l15) * 72 + ks * 32 + quad * 8];
                accS[fj] = __builtin_amdgcn_mfma_f32_16x16x32_bf16(aq[ks], bk, accS[fj], 0, 0, 0);
            }
        #pragma unroll
        for (int fj = 0; fj < 4; ++fj) {
            int mk = mask[n * SEQ + k0 + fj * 16 + l15];
            #pragma unroll
            for (int r = 0; r < 4; ++r)
                accS[fj][r] = mk ? accS[fj][r] : -1.0e9f;
        }
        float al[4];
        short* Ps = &QPs[w * 1152];
        #pragma unroll
        for (int r = 0; r < 4; ++r) {
            float mx = fmaxf(fmaxf(accS[0][r], accS[1][r]), fmaxf(accS[2][r], accS[3][r]));
            mx = fmaxf(mx, __shfl_xor(mx, 1, 64));
            mx = fmaxf(mx, __shfl_xor(mx, 2, 64));
            mx = fmaxf(mx, __shfl_xor(mx, 4, 64));
            mx = fmaxf(mx, __shfl_xor(mx, 8, 64));
            float mn = fmaxf(mold[r], mx);
            al[r] = exp2f(mold[r] - mn);
            mold[r] = mn;
            #pragma unroll
            for (int fj = 0; fj < 4; ++fj) {
                float p = exp2f(accS[fj][r] - mn);
                Ps[(quad * 4 + r) * 72 + fj * 16 + l15] = bfbits(p);
            }
        }
        #pragma unroll
        for (int fn = 0; fn < 5; ++fn)
            #pragma unroll
            for (int r = 0; r < 4; ++r) accO[fn][r] *= al[r];
        #pragma unroll
        for (int ks = 0; ks < 2; ++ks) {
            short8 ap = *(short8*)&Ps[l15 * 72 + ks * 32 + quad * 8];
            #pragma unroll
            for (int fn = 0; fn < 5; ++fn) {
                short8 bv = *(short8*)&Vs[(fn * 16 + l15) * 72 + ks * 32 + quad * 8];
                accO[fn] = __builtin_amdgcn_mfma_f32_16x16x32_bf16(ap, bv, accO[fn], 0, 0, 0);
            }
        }
    }
    // epilogue: unnormalized O + (m, l); l = col 0 of accO[4]
    bf16* Pob = (sp < 2) ? PoA : PoB;
    #pragma unroll
    for (int r = 0; r < 4; ++r) {
        float ls = __shfl(accO[4][r], lane & 48);
        int row = q0 + w * 16 + quad * 4 + r;
        size_t gtok = tokbase + row;
        bf16* dst = Pob + ((size_t)(sp & 1) * NS_TOK + gtok) * DMODEL + hh * HDIM;
        #pragma unroll
        for (int fn = 0; fn < 4; ++fn)
            dst[fn * 16 + l15] = f2bf(accO[fn][r]);
        if (l15 == 0) {
            Mm[((size_t)sp * NS_TOK + gtok) * NHEAD + hh] = mold[r];
            Ll[((size_t)sp * NS_TOK + gtok) * NHEAD + hh] = ls;
        }
    }
}

// ---------------- combine K-splits (2 or 4) ----------------
__global__ __launch_bounds__(256) void k_comb(const bf16* __restrict__ PoA,
    const bf16* __restrict__ PoB, const float* __restrict__ Mm,
    const float* __restrict__ Ll, bf16* __restrict__ Ab, int nsplit) {
    int tok = blockIdx.x * 4 + (threadIdx.x >> 6);
    int lane = threadIdx.x & 63;
    int hh = lane >> 3;
    float m = -1.0e38f;
    for (int s = 0; s < nsplit; ++s)
        m = fmaxf(m, Mm[((size_t)s * NS_TOK + tok) * NHEAD + hh]);
    float L = 0.f, wgt[4];
    for (int s = 0; s < nsplit; ++s) {
        wgt[s] = exp2f(Mm[((size_t)s * NS_TOK + tok) * NHEAD + hh] - m);
        L += Ll[((size_t)s * NS_TOK + tok) * NHEAD + hh] * wgt[s];
    }
    float inv = 1.f / L;
    float acc[8] = {0.f, 0.f, 0.f, 0.f, 0.f, 0.f, 0.f, 0.f};
    for (int s = 0; s < nsplit; ++s) {
        const bf16* base = ((s < 2) ? PoA : PoB) +
                           ((size_t)(s & 1) * NS_TOK + tok) * DMODEL + lane * 8;
        uint4 u = *(const uint4*)base;
        const unsigned int* p = (const unsigned int*)&u;
        #pragma unroll
        for (int j = 0; j < 4; ++j) {
            float2 f = bf2x2(p[j]);
            acc[j * 2]     += f.x * wgt[s];
            acc[j * 2 + 1] += f.y * wgt[s];
        }
    }
    bf16* dst = Ab + (size_t)tok * DMODEL + lane * 8;
    #pragma unroll
    for (int j = 0; j < 8; ++j) dst[j] = f2bf(acc[j] * inv);
}

// ---------------- fast MFMA GEMM (global_load_lds staging), direct epilogue -----
template<int MT, int NT, bool RELU>
__global__ __launch_bounds__(256) void k_gemm_f(const bf16* __restrict__ A,
    const bf16* __restrict__ W, const float* __restrict__ bias, int K, int N,
    const float* __restrict__ resid, float* __restrict__ outF, bf16* __restrict__ outB) {
    constexpr int FI = MT / 32;
    constexpr int FJ = NT / 32;
    __shared__ __align__(16) short As[MT * 32];
    __shared__ __align__(16) short Bs[NT * 32];
    int t = threadIdx.x, lane = t & 63, w = t >> 6;
    int m0 = blockIdx.x * MT, n0 = blockIdx.y * NT;
    int wrow = (w >> 1) * (MT / 2), wcol = (w & 1) * (NT / 2);
    int quad = lane >> 4, mrow = lane & 15;
    int lr = lane >> 2, lc = (lane & 3) * 8;
    floatx4 acc[FI][FJ];
    #pragma unroll
    for (int fi = 0; fi < FI; ++fi)
        #pragma unroll
        for (int fj = 0; fj < FJ; ++fj)
            #pragma unroll
            for (int r = 0; r < 4; ++r) acc[fi][fj][r] = 0.f;

    for (int k0 = 0; k0 < K; k0 += 32) {
        __syncthreads();
        #pragma unroll
        for (int i = 0; i < MT / 64; ++i) {
            int rbase = (i * 4 + w) * 16;
            gl2lds16(A + (size_t)(m0 + rbase + lr) * K + k0 + lc, &As[rbase * 32]);
        }
        #pragma unroll
        for (int i = 0; i < NT / 64; ++i) {
            int rbase = (i * 4 + w) * 16;
            gl2lds16(W + (size_t)(n0 + rbase + lr) * K + k0 + lc, &Bs[rbase * 32]);
        }
        __syncthreads();
        short8 af[FI], bfr[FJ];
        #pragma unroll
        for (int fi = 0; fi < FI; ++fi)
            af[fi] = *(short8*)&As[(wrow + fi * 16 + mrow) * 32 + quad * 8];
        #pragma unroll
        for (int fj = 0; fj < FJ; ++fj)
            bfr[fj] = *(short8*)&Bs[(wcol + fj * 16 + mrow) * 32 + quad * 8];
        #pragma unroll
        for (int fi = 0; fi < FI; ++fi)
            #pragma unroll
            for (int fj = 0; fj < FJ; ++fj)
                acc[fi][fj] = __builtin_amdgcn_mfma_f32_16x16x32_bf16(
                    af[fi], bfr[fj], acc[fi][fj], 0, 0, 0);
    }
    #pragma unroll
    for (int fi = 0; fi < FI; ++fi)
        #pragma unroll
        for (int fj = 0; fj < FJ; ++fj) {
            int col = n0 + wcol + fj * 16 + mrow;
            float bv = bias[col];
            #pragma unroll
            for (int r = 0; r < 4; ++r) {
                int row = m0 + wrow + fi * 16 + quad * 4 + r;
                float v = acc[fi][fj][r] + bv;
                if (RELU) {
                    outB[(size_t)row * N + col] = f2bf(fmaxf(v, 0.f));
                } else {
                    outF[(size_t)row * N + col] = v + resid[(size_t)row * N + col];
                }
            }
        }
}

// ---------------- fast MFMA GEMM, split-K(2), raw fp32 partials ----------------
template<int MT, int NT>
__global__ __launch_bounds__(256) void k_gemm_sk(const bf16* __restrict__ A,
    const bf16* __restrict__ W, int K, int N,
    float* __restrict__ out0, float* __restrict__ out1) {
    constexpr int FI = MT / 32;
    constexpr int FJ = NT / 32;
    __shared__ __align__(16) short As[MT * 32];
    __shared__ __align__(16) short Bs[NT * 32];
    int t = threadIdx.x, lane = t & 63, w = t >> 6;
    int m0 = blockIdx.x * MT, n0 = blockIdx.y * NT;
    int wrow = (w >> 1) * (MT / 2), wcol = (w & 1) * (NT / 2);
    int quad = lane >> 4, mrow = lane & 15;
    int lr = lane >> 2, lc = (lane & 3) * 8;
    floatx4 acc[FI][FJ];
    #pragma unroll
    for (int fi = 0; fi < FI; ++fi)
        #pragma unroll
        for (int fj = 0; fj < FJ; ++fj)
            #pragma unroll
            for (int r = 0; r < 4; ++r) acc[fi][fj][r] = 0.f;

    int kh = K >> 1;
    int kbeg = blockIdx.z * kh;
    for (int k0 = kbeg; k0 < kbeg + kh; k0 += 32) {
        __syncthreads();
        #pragma unroll
        for (int i = 0; i < MT / 64; ++i) {
            int rbase = (i * 4 + w) * 16;
            gl2lds16(A + (size_t)(m0 + rbase + lr) * K + k0 + lc, &As[rbase * 32]);
        }
        #pragma unroll
        for (int i = 0; i < NT / 64; ++i) {
            int rbase = (i * 4 + w) * 16;
            gl2lds16(W + (size_t)(n0 + rbase + lr) * K + k0 + lc, &Bs[rbase * 32]);
        }
        __syncthreads();
        short8 af[FI], bfr[FJ];
        #pragma unroll
        for (int fi = 0; fi < FI; ++fi)
            af[fi] = *(short8*)&As[(wrow + fi * 16 + mrow) * 32 + quad * 8];
        #pragma unroll
        for (int fj = 0; fj < FJ; ++fj)
            bfr[fj] = *(short8*)&Bs[(wcol + fj * 16 + mrow) * 32 + quad * 8];
        #pragma unroll
        for (int fi = 0; fi < FI; ++fi)
            #pragma unroll
            for (int fj = 0; fj < FJ; ++fj)
                acc[fi][fj] = __builtin_amdgcn_mfma_f32_16x16x32_bf16(
                    af[fi], bfr[fj], acc[fi][fj], 0, 0, 0);
    }
    float* out = blockIdx.z ? out1 : out0;
    #pragma unroll
    for (int fi = 0; fi < FI; ++fi)
        #pragma unroll
        for (int fj = 0; fj < FJ; ++fj) {
            int col = n0 + wcol + fj * 16 + mrow;
            #pragma unroll
            for (int r = 0; r < 4; ++r) {
                int row = m0 + wrow + fi * 16 + quad * 4 + r;
                out[(size_t)row * N + col] = acc[fi][fj][r];
            }
        }
}

// ---------------- slow fp32-weight GEMM (tier-0 fallback, round-7 code) --------
template<int MT, bool RELU>
__global__ __launch_bounds__(256) void k_gemm(const bf16* __restrict__ A,
    const float* __restrict__ Wf, const float* __restrict__ bias, int K, int N,
    const float* __restrict__ resid, float* __restrict__ outF, bf16* __restrict__ outB) {
    constexpr int FI = 4;
    constexpr int FJ = (MT == 128) ? 4 : 2;
    __shared__ short As[MT * 40];
    __shared__ short Bs[128 * 40];
    int t = threadIdx.x, lane = t & 63, w = t >> 6;
    int m0 = blockIdx.x * MT, n0 = blockIdx.y * 128;
    int wrow = (MT == 128) ? (w >> 1) * 64 : 0;
    int wcol = (MT == 128) ? (w & 1) * 64 : w * 32;
    int quad = lane >> 4, mrow = lane & 15;
    floatx4 acc[FI][FJ];
    #pragma unroll
    for (int fi = 0; fi < FI; ++fi)
        #pragma unroll
        for (int fj = 0; fj < FJ; ++fj)
            #pragma unroll
            for (int r = 0; r < 4; ++r) acc[fi][fj][r] = 0.f;
    for (int k0 = 0; k0 < K; k0 += 32) {
        __syncthreads();
        #pragma unroll
        for (int i = 0; i < MT / 64; ++i) {
            int idx = t + i * 256;
            int row = idx >> 2, q = idx & 3;
            uint4 u = *(const uint4*)(A + (size_t)(m0 + row) * K + k0 + q * 8);
            *(uint4*)&As[row * 40 + q * 8] = u;
        }
        #pragma unroll
        for (int i = 0; i < 2; ++i) {
            int idx = t + i * 256;
            int row = idx >> 2, q = idx & 3;
            const float* src = Wf + (size_t)(n0 + row) * K + k0 + q * 8;
            float4 f0 = *(const float4*)src;
            float4 f1 = *(const float4*)(src + 4);
            short8 sv;
            sv[0] = bfbits(f0.x); sv[1] = bfbits(f0.y);
            sv[2] = bfbits(f0.z); sv[3] = bfbits(f0.w);
            sv[4] = bfbits(f1.x); sv[5] = bfbits(f1.y);
            sv[6] = bfbits(f1.z); sv[7] = bfbits(f1.w);
            *(short8*)&Bs[row * 40 + q * 8] = sv;
        }
        __syncthreads();
        short8 af[FI], bfr[FJ];
        #pragma unroll
        for (int fi = 0; fi < FI; ++fi)
            af[fi] = *(short8*)&As[(wrow + fi * 16 + mrow) * 40 + quad * 8];
        #pragma unroll
        for (int fj = 0; fj < FJ; ++fj)
            bfr[fj] = *(short8*)&Bs[(wcol + fj * 16 + mrow) * 40 + quad * 8];
        #pragma unroll
        for (int fi = 0; fi < FI; ++fi)
            #pragma unroll
            for (int fj = 0; fj < FJ; ++fj)
                acc[fi][fj] = __builtin_amdgcn_mfma_f32_16x16x32_bf16(
                    af[fi], bfr[fj], acc[fi][fj], 0, 0, 0);
    }
    #pragma unroll
    for (int fi = 0; fi < FI; ++fi)
        #pragma unroll
        for (int fj = 0; fj < FJ; ++fj) {
            int col = n0 + wcol + fj * 16 + mrow;
            float bv = bias[col];
            #pragma unroll
            for (int r = 0; r < 4; ++r) {
                int row = m0 + wrow + fi * 16 + quad * 4 + r;
                float v = acc[fi][fj][r] + bv;
                if (RELU) {
                    outB[(size_t)row * N + col] = f2bf(fmaxf(v, 0.f));
                } else {
                    outF[(size_t)row * N + col] = v + resid[(size_t)row * N + col];
                }
            }
        }
}

// ---------------- LayerNorm (plain, tiers 0/1) ----------------
__global__ __launch_bounds__(256) void k_ln(const float* __restrict__ P,
    const float* __restrict__ g, const float* __restrict__ b,
    float* __restrict__ outF, bf16* __restrict__ outB) {
    int row = blockIdx.x * 4 + (threadIdx.x >> 6);
    int lane = threadIdx.x & 63;
    const float* p = P + (size_t)row * DMODEL + lane * 8;
    float4 a = *(const float4*)p;
    float4 c = *(const float4*)(p + 4);
    float s = a.x + a.y + a.z + a.w + c.x + c.y + c.z + c.w;
    #pragma unroll
    for (int off = 32; off > 0; off >>= 1) s += __shfl_xor(s, off, 64);
    float mean = s * (1.f / DMODEL);
    float d[8] = {a.x - mean, a.y - mean, a.z - mean, a.w - mean,
                  c.x - mean, c.y - mean, c.z - mean, c.w - mean};
    float vs = 0.f;
    #pragma unroll
    for (int j = 0; j < 8; ++j) vs += d[j] * d[j];
    #pragma unroll
    for (int off = 32; off > 0; off >>= 1) vs += __shfl_xor(vs, off, 64);
    float rstd = rsqrtf(vs * (1.f / DMODEL) + 1e-5f);
    float4 g0 = *(const float4*)(g + lane * 8);
    float4 g1 = *(const float4*)(g + lane * 8 + 4);
    float4 b0 = *(const float4*)(b + lane * 8);
    float4 b1 = *(const float4*)(b + lane * 8 + 4);
    float o[8] = {d[0] * rstd * g0.x + b0.x, d[1] * rstd * g0.y + b0.y,
                  d[2] * rstd * g0.z + b0.z, d[3] * rstd * g0.w + b0.w,
                  d[4] * rstd * g1.x + b1.x, d[5] * rstd * g1.y + b1.y,
                  d[6] * rstd * g1.z + b1.z, d[7] * rstd * g1.w + b1.w};
    float* of = outF + (size_t)row * DMODEL + lane * 8;
    *(float4*)of       = make_float4(o[0], o[1], o[2], o[3]);
    *(float4*)(of + 4) = make_float4(o[4], o[5], o[6], o[7]);
    if (outB) {
        bf16* ob = outB + (size_t)row * DMODEL + lane * 8;
        #pragma unroll
        for (int j = 0; j < 8; ++j) ob[j] = f2bf(o[j]);
    }
}

// ---------------- fused: combine split-K partials + bias + resid + LN ----------
__global__ __launch_bounds__(256) void k_lncomb(const float* __restrict__ pp0,
    const float* __restrict__ pp1, const float* __restrict__ bias,
    const float* __restrict__ resid, const float* __restrict__ g,
    const float* __restrict__ b, float* __restrict__ outF, bf16* __restrict__ outB) {
    int row = blockIdx.x * 4 + (threadIdx.x >> 6);
    int lane = threadIdx.x & 63;
    size_t idx = (size_t)row * DMODEL + lane * 8;
    float4 a0 = *(const float4*)(pp0 + idx),  a1 = *(const float4*)(pp0 + idx + 4);
    float4 c0 = *(const float4*)(pp1 + idx),  c1 = *(const float4*)(pp1 + idx + 4);
    float4 r0 = *(const float4*)(resid + idx), r1 = *(const float4*)(resid + idx + 4);
    float4 q0 = *(const float4*)(bias + lane * 8), q1 = *(const float4*)(bias + lane * 8 + 4);
    float v[8] = {a0.x + c0.x + r0.x + q0.x, a0.y + c0.y + r0.y + q0.y,
                  a0.z + c0.z + r0.z + q0.z, a0.w + c0.w + r0.w + q0.w,
                  a1.x + c1.x + r1.x + q1.x, a1.y + c1.y + r1.y + q1.y,
                  a1.z + c1.z + r1.z + q1.z, a1.w + c1.w + r1.w + q1.w};
    float s = 0.f;
    #pragma unroll
    for (int j = 0; j < 8; ++j) s += v[j];
    #pragma unroll
    for (int off = 32; off > 0; off >>= 1) s += __shfl_xor(s, off, 64);
    float mean = s * (1.f / DMODEL);
    float vs = 0.f;
    #pragma unroll
    for (int j = 0; j < 8; ++j) { v[j] -= mean; vs += v[j] * v[j]; }
    #pragma unroll
    for (int off = 32; off > 0; off >>= 1) vs += __shfl_xor(vs, off, 64);
    float rstd = rsqrtf(vs * (1.f / DMODEL) + 1e-5f);
    float4 g0 = *(const float4*)(g + lane * 8);
    float4 g1 = *(const float4*)(g + lane * 8 + 4);
    float4 b0 = *(const float4*)(b + lane * 8);
    float4 b1 = *(const float4*)(b + lane * 8 + 4);
    float o[8] = {v[0] * rstd * g0.x + b0.x, v[1] * rstd * g0.y + b0.y,
                  v[2] * rstd * g0.z + b0.z, v[3] * rstd * g0.w + b0.w,
                  v[4] * rstd * g1.x + b1.x, v[5] * rstd * g1.y + b1.y,
                  v[6] * rstd * g1.z + b1.z, v[7] * rstd * g1.w + b1.w};
    float* of = outF + idx;
    *(float4*)of       = make_float4(o[0], o[1], o[2], o[3]);
    *(float4*)(of + 4) = make_float4(o[4], o[5], o[6], o[7]);
    if (outB) {
        bf16* ob = outB + idx;
        #pragma unroll
        for (int j = 0; j < 8; ++j) ob[j] = f2bf(o[j]);
    }
}

extern "C" void kernel_launch(void* const* d_in, const int* in_sizes, int n_in,
                              void* d_out, int out_size, void* d_ws, size_t ws_size,
                              hipStream_t stream) {
    const int*   src  = (const int*)d_in[0];
    const int*   mask = (const int*)d_in[1];
    const float* emb  = (const float*)d_in[2];
    const float* Wq   = (const float*)d_in[3];
    const float* bq   = (const float*)d_in[4];
    const float* Wk   = (const float*)d_in[5];
    const float* bk   = (const float*)d_in[6];
    const float* Wv   = (const float*)d_in[7];
    const float* bv   = (const float*)d_in[8];
    const float* Wo   = (const float*)d_in[9];
    const float* bo   = (const float*)d_in[10];
    const float* W1   = (const float*)d_in[11];
    const float* b1   = (const float*)d_in[12];
    const float* W2   = (const float*)d_in[13];
    const float* b2   = (const float*)d_in[14];
    const float* ln1g = (const float*)d_in[15];
    const float* ln1b = (const float*)d_in[16];
    const float* ln2g = (const float*)d_in[17];
    const float* ln2b = (const float*)d_in[18];

    char* base = (char*)d_ws;
    float* h   = (float*)base;                       // 8,388,608
    float* hbf = (float*)(base + 8388608);           // 4,194,304 (hb + Mm/Ll alias)
    bf16*  hb  = (bf16*)hbf;
    float* Mm  = hbf;                                // [4][NS][H] = 512 KB
    float* Ll  = hbf + 4 * NS_TOK * NHEAD;           // 512 KB
    float* Pp0 = (float*)(base + 12582912);          // 8,388,608
    bf16*  Qb  = (bf16*)(base + 20971520);           // 4 x 4,194,304
    bf16*  Kb  = (bf16*)(base + 25165824);
    bf16*  Vt  = (bf16*)(base + 29360128);
    bf16*  Ab  = (bf16*)(base + 33554432);
    bf16*  F1b = Qb;                                  // aliases Qb..Ab
    bf16*  Wob = (bf16*)(base + 37748736);           // 3,145,728
    bf16*  W1b = (bf16*)(base + 40894464);           // 12,582,912
    bf16*  W2b = (bf16*)(base + 53477376);           // 12,582,912
    float* Pp1 = (float*)(base + 66060288);          // 8,388,608 -> 74,448,896
    int tier = (ws_size >= 74448896ull) ? 2 : ((ws_size >= 66060288ull) ? 1 : 0);

    if (tier >= 1) {
        k_conv<<<(6 * DMODEL * DMODEL) / 2048, 256, 0, stream>>>(Wo, Wob, 6 * DMODEL * DMODEL);
        k_conv<<<(6 * FFDIM * DMODEL) / 2048, 256, 0, stream>>>(W1, W1b, 6 * FFDIM * DMODEL);
        k_conv<<<(6 * FFDIM * DMODEL) / 2048, 256, 0, stream>>>(W2, W2b, 6 * FFDIM * DMODEL);
    }
    k_embed<<<NS_TOK, 256, 0, stream>>>(src, emb, h, hb);

    int ns_l2 = (tier == 2) ? 2 : 1;
    int nsplit = 1 << ns_l2;
    bf16* PoA = (bf16*)Pp0;
    bf16* PoB = (tier == 2) ? (bf16*)Pp1 : (bf16*)Pp0;

    for (int l = 0; l < 6; ++l) {
        k_qkv<<<dim3(NS_TOK / 64, NHEAD), 256, 0, stream>>>(hb,
            Wq + (size_t)l * HDIM * HDIM, bq + l * HDIM,
            Wk + (size_t)l * HDIM * HDIM, bk + l * HDIM,
            Wv + (size_t)l * HDIM * HDIM, bv + l * HDIM,
            Qb, Kb, Vt);
        k_attn<<<dim3(SEQ / 64, NHEAD, NB * nsplit), 256, 0, stream>>>(
            Qb, Kb, Vt, mask, PoA, PoB, Mm, Ll, ns_l2);
        k_comb<<<NS_TOK / 4, 256, 0, stream>>>(PoA, PoB, Mm, Ll, Ab, nsplit);

        float* lnout = (l == 5) ? (float*)d_out : h;
        bf16* lnoutB = (l == 5) ? nullptr : hb;

        if (tier == 2) {
            k_gemm_sk<64, 128><<<dim3(NS_TOK / 64, DMODEL / 128, 2), 256, 0, stream>>>(
                Ab, Wob + (size_t)l * DMODEL * DMODEL, DMODEL, DMODEL, Pp0, Pp1);
            k_lncomb<<<NS_TOK / 4, 256, 0, stream>>>(Pp0, Pp1, bo + l * DMODEL, h,
                ln1g + l * DMODEL, ln1b + l * DMODEL, h, hb);
            k_gemm_f<128, 128, true><<<dim3(NS_TOK / 128, FFDIM / 128), 256, 0, stream>>>(
                hb, W1b + (size_t)l * FFDIM * DMODEL, b1 + l * FFDIM,
                DMODEL, FFDIM, nullptr, nullptr, F1b);
            k_gemm_sk<64, 128><<<dim3(NS_TOK / 64, DMODEL / 128, 2), 256, 0, stream>>>(
                F1b, W2b + (size_t)l * DMODEL * FFDIM, FFDIM, DMODEL, Pp0, Pp1);
            k_lncomb<<<NS_TOK / 4, 256, 0, stream>>>(Pp0, Pp1, b2 + l * DMODEL, h,
                ln2g + l * DMODEL, ln2b + l * DMODEL, lnout, lnoutB);
        } else if (tier == 1) {
            k_gemm_f<64, 128, false><<<dim3(NS_TOK / 64, DMODEL / 128), 256, 0, stream>>>(
                Ab, Wob + (size_t)l * DMODEL * DMODEL, bo + l * DMODEL,
                DMODEL, DMODEL, h, Pp0, nullptr);
            k_ln<<<NS_TOK / 4, 256, 0, stream>>>(Pp0, ln1g + l * DMODEL, ln1b + l * DMODEL, h, hb);
            k_gemm_f<128, 128, true><<<dim3(NS_TOK / 128, FFDIM / 128), 256, 0, stream>>>(
                hb, W1b + (size_t)l * FFDIM * DMODEL, b1 + l * FFDIM,
                DMODEL, FFDIM, nullptr, nullptr, F1b);
            k_gemm_f<64, 128, false><<<dim3(NS_TOK / 64, DMODEL / 128), 256, 0, stream>>>(
                F1b, W2b + (size_t)l * DMODEL * FFDIM, b2 + l * DMODEL,
                FFDIM, DMODEL, h, Pp0, nullptr);
            k_ln<<<NS_TOK / 4, 256, 0, stream>>>(Pp0, ln2g + l * DMODEL, ln2b + l * DMODEL, lnout, lnoutB);
        } else {
            k_gemm<64, false><<<dim3(NS_TOK / 64, DMODEL / 128), 256, 0, stream>>>(
                Ab, Wo + (size_t)l * DMODEL * DMODEL, bo + l * DMODEL,
                DMODEL, DMODEL, h, Pp0, nullptr);
            k_ln<<<NS_TOK / 4, 256, 0, stream>>>(Pp0, ln1g + l * DMODEL, ln1b + l * DMODEL, h, hb);
            k_gemm<128, true><<<dim3(NS_TOK / 128, FFDIM / 128), 256, 0, stream>>>(
                hb, W1 + (size_t)l * FFDIM * DMODEL, b1 + l * FFDIM,
                DMODEL, FFDIM, nullptr, nullptr, F1b);
            k_gemm<64, false><<<dim3(NS_TOK / 64, DMODEL / 128), 256, 0, stream>>>(
                F1b, W2 + (size_t)l * DMODEL * FFDIM, b2 + l * DMODEL,
                FFDIM, DMODEL, h, Pp0, nullptr);
            k_ln<<<NS_TOK / 4, 256, 0, stream>>>(Pp0, ln2g + l * DMODEL, ln2b + l * DMODEL, lnout, lnoutB);
        }
    }
}